// Round 1
// baseline (1471.385 us; speedup 1.0000x reference)
//
#include <hip/hip_runtime.h>
#include <hip/hip_bf16.h>

#define N_NODES 50000
#define N_EDGES 800000
#define N_GRAPHS 500
#define H 90

// ---------------- count in-degree per dst node ----------------
__global__ __launch_bounds__(256) void count_kernel(const int* __restrict__ dst,
                                                    float* __restrict__ cnt) {
    int e = blockIdx.x * blockDim.x + threadIdx.x;
    if (e < N_EDGES) atomicAdd(&cnt[dst[e]], 1.0f);
}

// ---------------- scatter: aggr[dst] += x[src], thread per (edge,h) ----------------
__global__ __launch_bounds__(256) void scatter_kernel(const float* __restrict__ xin,
                                                      const int* __restrict__ src,
                                                      const int* __restrict__ dst,
                                                      float* __restrict__ aggr) {
    const long long total = (long long)N_EDGES * H;
    long long stride = (long long)gridDim.x * blockDim.x;
    for (long long idx = blockIdx.x * (long long)blockDim.x + threadIdx.x;
         idx < total; idx += stride) {
        int e = (int)(idx / H);
        int h = (int)(idx - (long long)e * H);
        int s = src[e];
        int d = dst[e];
        atomicAdd(&aggr[(long long)d * H + h], xin[(long long)s * H + h]);
    }
}

// ---------------- combine: out = relu(aggr/cnt @ Wl^T + bl + xin @ Wr^T) ----------------
#define TILE 16
__global__ __launch_bounds__(256) void combine_kernel(const float* __restrict__ xin,
                                                      const float* __restrict__ aggr,
                                                      const float* __restrict__ cnt,
                                                      const float* __restrict__ Wl,
                                                      const float* __restrict__ bl,
                                                      const float* __restrict__ Wr,
                                                      float* __restrict__ out) {
    __shared__ float sWl[H * H];
    __shared__ float sWr[H * H];
    __shared__ float sb[H];
    __shared__ float sx[TILE][H];
    __shared__ float sa[TILE][H];

    for (int i = threadIdx.x; i < H * H; i += blockDim.x) {
        sWl[i] = Wl[i];
        sWr[i] = Wr[i];
    }
    for (int i = threadIdx.x; i < H; i += blockDim.x) sb[i] = bl[i];

    int node0 = blockIdx.x * TILE;   // 50000 = 3125 * 16 exactly
    __syncthreads();

    for (int i = threadIdx.x; i < TILE * H; i += blockDim.x) {
        int r = i / H, c = i - r * H;
        long long g = (long long)(node0 + r) * H + c;
        sx[r][c] = xin[g];
        float cc = cnt[node0 + r];
        sa[r][c] = aggr[g] / fmaxf(cc, 1.0f);
    }
    __syncthreads();

    for (int i = threadIdx.x; i < TILE * H; i += blockDim.x) {
        int r = i / H, h = i - r * H;
        float acc = sb[h];
        #pragma unroll 6
        for (int k = 0; k < H; ++k) {
            acc += sa[r][k] * sWl[h * H + k];
            acc += sx[r][k] * sWr[h * H + k];
        }
        out[(long long)(node0 + r) * H + h] = fmaxf(acc, 0.0f);
    }
}

// ---------------- pooling ----------------
__global__ __launch_bounds__(256) void pool_cnt_kernel(const int* __restrict__ batch,
                                                       float* __restrict__ gc) {
    int i = blockIdx.x * blockDim.x + threadIdx.x;
    if (i < N_NODES) atomicAdd(&gc[batch[i]], 1.0f);
}

__global__ __launch_bounds__(256) void pool_sum_kernel(const float* __restrict__ h3,
                                                       const int* __restrict__ batch,
                                                       float* __restrict__ gs) {
    const int total = N_NODES * H;
    int stride = gridDim.x * blockDim.x;
    for (int idx = blockIdx.x * blockDim.x + threadIdx.x; idx < total; idx += stride) {
        int i = idx / H;
        int h = idx - i * H;
        int g = batch[i];
        atomicAdd(&gs[g * H + h], h3[idx]);
    }
}

// ---------------- final MLP: [500,90] -> fc1(32) relu -> fc2(1) ----------------
__global__ __launch_bounds__(64) void mlp_kernel(const float* __restrict__ gs,
                                                 const float* __restrict__ gc,
                                                 const float* __restrict__ fc1_w,
                                                 const float* __restrict__ fc1_b,
                                                 const float* __restrict__ fc2_w,
                                                 const float* __restrict__ fc2_b,
                                                 float* __restrict__ out) {
    int g = blockIdx.x;
    int t = threadIdx.x;
    __shared__ float h4[H];
    float inv = 1.0f / fmaxf(gc[g], 1.0f);
    for (int k = t; k < H; k += 64) h4[k] = gs[g * H + k] * inv;
    __syncthreads();
    float v = 0.0f;
    if (t < 32) {
        float acc = fc1_b[t];
        #pragma unroll 6
        for (int k = 0; k < H; ++k) acc += h4[k] * fc1_w[t * H + k];
        v = fmaxf(acc, 0.0f) * fc2_w[t];
    }
    for (int off = 16; off; off >>= 1) v += __shfl_down(v, off, 32);
    if (t == 0) out[g] = v + fc2_b[0];
}

extern "C" void kernel_launch(void* const* d_in, const int* in_sizes, int n_in,
                              void* d_out, int out_size, void* d_ws, size_t ws_size,
                              hipStream_t stream) {
    const float* x     = (const float*)d_in[0];
    const int*   ei    = (const int*)d_in[1];
    const int*   batch = (const int*)d_in[2];
    const float* W1l = (const float*)d_in[3];
    const float* b1l = (const float*)d_in[4];
    const float* W1r = (const float*)d_in[5];
    const float* W2l = (const float*)d_in[6];
    const float* b2l = (const float*)d_in[7];
    const float* W2r = (const float*)d_in[8];
    const float* W3l = (const float*)d_in[9];
    const float* b3l = (const float*)d_in[10];
    const float* W3r = (const float*)d_in[11];
    const float* fc1_w = (const float*)d_in[12];
    const float* fc1_b = (const float*)d_in[13];
    const float* fc2_w = (const float*)d_in[14];
    const float* fc2_b = (const float*)d_in[15];

    const int* src = ei;
    const int* dst = ei + N_EDGES;

    float* ws   = (float*)d_ws;
    float* cnt  = ws;                      // N_NODES
    float* gs   = cnt + N_NODES;           // N_GRAPHS*H
    float* gc   = gs + N_GRAPHS * H;       // N_GRAPHS
    float* aggr = gc + N_GRAPHS;           // N_NODES*H
    float* bufA = aggr + (long long)N_NODES * H;
    float* bufB = bufA + (long long)N_NODES * H;

    float* out = (float*)d_out;

    const int edgeBlocks = N_EDGES / 256;          // 3125 exact
    const int tileBlocks = N_NODES / TILE;         // 3125 exact
    const int gsBlocks   = 2048;

    // degree counts (shared by all 3 layers)
    hipMemsetAsync(cnt, 0, N_NODES * sizeof(float), stream);
    count_kernel<<<edgeBlocks, 256, 0, stream>>>(dst, cnt);

    // layer 1: x -> bufA
    hipMemsetAsync(aggr, 0, (size_t)N_NODES * H * sizeof(float), stream);
    scatter_kernel<<<gsBlocks, 256, 0, stream>>>(x, src, dst, aggr);
    combine_kernel<<<tileBlocks, 256, 0, stream>>>(x, aggr, cnt, W1l, b1l, W1r, bufA);

    // layer 2: bufA -> bufB
    hipMemsetAsync(aggr, 0, (size_t)N_NODES * H * sizeof(float), stream);
    scatter_kernel<<<gsBlocks, 256, 0, stream>>>(bufA, src, dst, aggr);
    combine_kernel<<<tileBlocks, 256, 0, stream>>>(bufA, aggr, cnt, W2l, b2l, W2r, bufB);

    // layer 3: bufB -> bufA
    hipMemsetAsync(aggr, 0, (size_t)N_NODES * H * sizeof(float), stream);
    scatter_kernel<<<gsBlocks, 256, 0, stream>>>(bufB, src, dst, aggr);
    combine_kernel<<<tileBlocks, 256, 0, stream>>>(bufB, aggr, cnt, W3l, b3l, W3r, bufA);

    // global mean pool
    hipMemsetAsync(gs, 0, (N_GRAPHS * H + N_GRAPHS) * sizeof(float), stream);
    pool_cnt_kernel<<<(N_NODES + 255) / 256, 256, 0, stream>>>(batch, gc);
    pool_sum_kernel<<<gsBlocks, 256, 0, stream>>>(bufA, batch, gs);

    // MLP head
    mlp_kernel<<<N_GRAPHS, 64, 0, stream>>>(gs, gc, fc1_w, fc1_b, fc2_w, fc2_b, out);
}

// Round 2
// 533.581 us; speedup vs baseline: 2.7576x; 2.7576x over previous
//
#include <hip/hip_runtime.h>
#include <hip/hip_bf16.h>

#define N_NODES 50000
#define N_EDGES 800000
#define N_GRAPHS 500
#define H 90

// ================= CSR build =================
__global__ __launch_bounds__(256) void deg_kernel(const int* __restrict__ dst,
                                                  int* __restrict__ deg) {
    int e = blockIdx.x * blockDim.x + threadIdx.x;
    if (e < N_EDGES) atomicAdd(&deg[dst[e]], 1);
}

#define SCAN_B 512
#define NSB ((N_NODES + SCAN_B - 1) / SCAN_B)   // 98
__global__ __launch_bounds__(SCAN_B) void scan1_kernel(const int* __restrict__ deg,
                                                       int* __restrict__ rowloc,
                                                       int* __restrict__ bsum) {
    __shared__ int s[SCAN_B];
    int t = threadIdx.x;
    int i = blockIdx.x * SCAN_B + t;
    int v = (i < N_NODES) ? deg[i] : 0;
    s[t] = v;
    __syncthreads();
    for (int off = 1; off < SCAN_B; off <<= 1) {
        int u = (t >= off) ? s[t - off] : 0;
        __syncthreads();
        s[t] += u;
        __syncthreads();
    }
    if (i < N_NODES) rowloc[i] = s[t] - v;          // exclusive
    if (t == SCAN_B - 1) bsum[blockIdx.x] = s[t];   // block total
}

__global__ __launch_bounds__(128) void scan2_kernel(const int* __restrict__ bsum,
                                                    int* __restrict__ boff) {
    __shared__ int s[128];
    int t = threadIdx.x;
    int v = (t < NSB) ? bsum[t] : 0;
    s[t] = v;
    __syncthreads();
    for (int off = 1; off < 128; off <<= 1) {
        int u = (t >= off) ? s[t - off] : 0;
        __syncthreads();
        s[t] += u;
        __syncthreads();
    }
    boff[t] = s[t] - v;  // exclusive
}

__global__ __launch_bounds__(256) void scan3_kernel(const int* __restrict__ rowloc,
                                                    const int* __restrict__ boff,
                                                    int* __restrict__ rowptr) {
    int i = blockIdx.x * blockDim.x + threadIdx.x;
    if (i < N_NODES) rowptr[i] = rowloc[i] + boff[i / SCAN_B];
    else if (i == N_NODES) rowptr[i] = N_EDGES;
}

__global__ __launch_bounds__(256) void fill_kernel(const int* __restrict__ src,
                                                   const int* __restrict__ dst,
                                                   const int* __restrict__ rowptr,
                                                   int* __restrict__ fill,
                                                   int* __restrict__ csr) {
    int e = blockIdx.x * blockDim.x + threadIdx.x;
    if (e < N_EDGES) {
        int d = dst[e];
        int p = atomicAdd(&fill[d], 1);
        csr[rowptr[d] + p] = src[e];
    }
}

// ================= gather aggregation: aggrN[n] = mean_{s in N(n)} x[s] =================
// one wave per node; lane covers h=lane and h=64+lane
__global__ __launch_bounds__(256) void aggregate_kernel(const float* __restrict__ xin,
                                                        const int* __restrict__ rowptr,
                                                        const int* __restrict__ csr,
                                                        float* __restrict__ aggrN) {
    int wave = threadIdx.x >> 6;
    int lane = threadIdx.x & 63;
    int n = blockIdx.x * 4 + wave;     // 12500 * 4 = 50000 exact
    int r0 = rowptr[n];
    int r1 = rowptr[n + 1];
    float a0 = 0.0f, a1 = 0.0f;
    int j = r0;
    for (; j + 1 < r1; j += 2) {
        int s0 = csr[j];
        int s1 = csr[j + 1];
        const float* x0 = xin + (long long)s0 * H;
        const float* x1 = xin + (long long)s1 * H;
        a0 += x0[lane];
        a0 += x1[lane];
        if (lane < H - 64) { a1 += x0[64 + lane]; a1 += x1[64 + lane]; }
    }
    if (j < r1) {
        int s0 = csr[j];
        const float* x0 = xin + (long long)s0 * H;
        a0 += x0[lane];
        if (lane < H - 64) a1 += x0[64 + lane];
    }
    float inv = 1.0f / (float)max(r1 - r0, 1);
    float* o = aggrN + (long long)n * H;
    o[lane] = a0 * inv;
    if (lane < H - 64) o[64 + lane] = a1 * inv;
}

// ================= combine: out = relu(aggrN @ Wl^T + bl + x @ Wr^T) =================
// 64 nodes x 90 h per block; thread (tx,ty): 4 nodes x 6 h register tile.
#define BN 64
#define KP 92   // padded K (and LDS row stride), multiple of 4, rows 16B-aligned
__global__ __launch_bounds__(256) void combine_kernel(const float* __restrict__ xin,
                                                      const float* __restrict__ aggrN,
                                                      const float* __restrict__ Wl,
                                                      const float* __restrict__ bl,
                                                      const float* __restrict__ Wr,
                                                      float* __restrict__ out) {
    __shared__ __align__(16) float sA[BN][KP];
    __shared__ __align__(16) float sW[96][KP];
    __shared__ float sb[H];

    int tid = threadIdx.x;
    int tx = tid & 15;
    int ty = tid >> 4;
    int node0 = blockIdx.x * BN;

    for (int i = tid; i < H; i += 256) sb[i] = bl[i];

    float acc[4][6];
#pragma unroll
    for (int i = 0; i < 4; ++i)
#pragma unroll
        for (int jj = 0; jj < 6; ++jj) acc[i][jj] = 0.0f;

    for (int pass = 0; pass < 2; ++pass) {
        const float* Asrc = pass ? xin : aggrN;
        const float* Wsrc = pass ? Wr : Wl;
        __syncthreads();   // previous-pass LDS reads done before overwrite
        for (int idx = tid; idx < BN * H; idx += 256) {
            int r = idx / H, c = idx - r * H;
            int node = node0 + r;
            sA[r][c] = (node < N_NODES) ? Asrc[(long long)node * H + c] : 0.0f;
        }
        for (int idx = tid; idx < BN * 2; idx += 256) {
            int r = idx >> 1;
            sA[r][H + (idx & 1)] = 0.0f;
        }
        for (int idx = tid; idx < H * H; idx += 256) {
            int r = idx / H, c = idx - r * H;
            sW[r][c] = Wsrc[idx];
        }
        for (int idx = tid; idx < 96 * 2; idx += 256) {
            int r = idx >> 1;
            sW[r][H + (idx & 1)] = 0.0f;
        }
        __syncthreads();

        for (int k = 0; k < KP; k += 4) {
            float4 a[4];
            float4 w[6];
#pragma unroll
            for (int i = 0; i < 4; ++i)
                a[i] = *reinterpret_cast<const float4*>(&sA[ty * 4 + i][k]);
#pragma unroll
            for (int jj = 0; jj < 6; ++jj)
                w[jj] = *reinterpret_cast<const float4*>(&sW[tx + 16 * jj][k]);
#pragma unroll
            for (int i = 0; i < 4; ++i)
#pragma unroll
                for (int jj = 0; jj < 6; ++jj) {
                    acc[i][jj] += a[i].x * w[jj].x + a[i].y * w[jj].y +
                                  a[i].z * w[jj].z + a[i].w * w[jj].w;
                }
        }
    }

#pragma unroll
    for (int i = 0; i < 4; ++i) {
        int node = node0 + ty * 4 + i;
        if (node >= N_NODES) continue;
#pragma unroll
        for (int jj = 0; jj < 6; ++jj) {
            int h = tx + 16 * jj;
            if (h < H) out[(long long)node * H + h] = fmaxf(acc[i][jj] + sb[h], 0.0f);
        }
    }
}

// ================= pooling =================
__global__ __launch_bounds__(256) void pool_cnt_kernel(const int* __restrict__ batch,
                                                       float* __restrict__ gc) {
    int i = blockIdx.x * blockDim.x + threadIdx.x;
    if (i < N_NODES) atomicAdd(&gc[batch[i]], 1.0f);
}

__global__ __launch_bounds__(256) void pool_sum_kernel(const float* __restrict__ h3,
                                                       const int* __restrict__ batch,
                                                       float* __restrict__ gs) {
    const int total = N_NODES * H;
    int stride = gridDim.x * blockDim.x;
    for (int idx = blockIdx.x * blockDim.x + threadIdx.x; idx < total; idx += stride) {
        int i = idx / H;
        int h = idx - i * H;
        int g = batch[i];
        atomicAdd(&gs[g * H + h], h3[idx]);
    }
}

// ================= MLP head =================
__global__ __launch_bounds__(64) void mlp_kernel(const float* __restrict__ gs,
                                                 const float* __restrict__ gc,
                                                 const float* __restrict__ fc1_w,
                                                 const float* __restrict__ fc1_b,
                                                 const float* __restrict__ fc2_w,
                                                 const float* __restrict__ fc2_b,
                                                 float* __restrict__ out) {
    int g = blockIdx.x;
    int t = threadIdx.x;
    __shared__ float h4[H];
    float inv = 1.0f / fmaxf(gc[g], 1.0f);
    for (int k = t; k < H; k += 64) h4[k] = gs[g * H + k] * inv;
    __syncthreads();
    float v = 0.0f;
    if (t < 32) {
        float acc = fc1_b[t];
#pragma unroll 6
        for (int k = 0; k < H; ++k) acc += h4[k] * fc1_w[t * H + k];
        v = fmaxf(acc, 0.0f) * fc2_w[t];
    }
    for (int off = 16; off; off >>= 1) v += __shfl_down(v, off, 32);
    if (t == 0) out[g] = v + fc2_b[0];
}

extern "C" void kernel_launch(void* const* d_in, const int* in_sizes, int n_in,
                              void* d_out, int out_size, void* d_ws, size_t ws_size,
                              hipStream_t stream) {
    const float* x     = (const float*)d_in[0];
    const int*   ei    = (const int*)d_in[1];
    const int*   batch = (const int*)d_in[2];
    const float* W1l = (const float*)d_in[3];
    const float* b1l = (const float*)d_in[4];
    const float* W1r = (const float*)d_in[5];
    const float* W2l = (const float*)d_in[6];
    const float* b2l = (const float*)d_in[7];
    const float* W2r = (const float*)d_in[8];
    const float* W3l = (const float*)d_in[9];
    const float* b3l = (const float*)d_in[10];
    const float* W3r = (const float*)d_in[11];
    const float* fc1_w = (const float*)d_in[12];
    const float* fc1_b = (const float*)d_in[13];
    const float* fc2_w = (const float*)d_in[14];
    const float* fc2_b = (const float*)d_in[15];

    const int* src = ei;
    const int* dst = ei + N_EDGES;

    // ---- workspace layout ----
    int* deg    = (int*)d_ws;              // N_NODES
    int* fil    = deg + N_NODES;           // N_NODES
    int* rowloc = fil + N_NODES;           // N_NODES
    int* rowptr = rowloc + N_NODES;        // N_NODES + 1
    int* bsum   = rowptr + N_NODES + 1;    // 128
    int* boff   = bsum + 128;              // 128
    int* csr    = boff + 128;              // N_EDGES
    float* aggrN = (float*)(csr + N_EDGES);              // N_NODES*H
    float* bufA  = aggrN + (long long)N_NODES * H;
    float* bufB  = bufA + (long long)N_NODES * H;
    float* gs    = bufB + (long long)N_NODES * H;        // N_GRAPHS*H
    float* gc    = gs + N_GRAPHS * H;                    // N_GRAPHS

    float* out = (float*)d_out;

    const int edgeBlocks = (N_EDGES + 255) / 256;
    const int combBlocks = (N_NODES + BN - 1) / BN;      // 782
    const int aggBlocks  = N_NODES / 4;                  // 12500

    // ---- CSR build (every call; deterministic work) ----
    hipMemsetAsync(deg, 0, 2 * N_NODES * sizeof(int), stream);  // deg + fil
    deg_kernel<<<edgeBlocks, 256, 0, stream>>>(dst, deg);
    scan1_kernel<<<NSB, SCAN_B, 0, stream>>>(deg, rowloc, bsum);
    scan2_kernel<<<1, 128, 0, stream>>>(bsum, boff);
    scan3_kernel<<<(N_NODES + 256) / 256, 256, 0, stream>>>(rowloc, boff, rowptr);
    fill_kernel<<<edgeBlocks, 256, 0, stream>>>(src, dst, rowptr, fil, csr);

    // ---- layer 1: x -> bufA ----
    aggregate_kernel<<<aggBlocks, 256, 0, stream>>>(x, rowptr, csr, aggrN);
    combine_kernel<<<combBlocks, 256, 0, stream>>>(x, aggrN, W1l, b1l, W1r, bufA);

    // ---- layer 2: bufA -> bufB ----
    aggregate_kernel<<<aggBlocks, 256, 0, stream>>>(bufA, rowptr, csr, aggrN);
    combine_kernel<<<combBlocks, 256, 0, stream>>>(bufA, aggrN, W2l, b2l, W2r, bufB);

    // ---- layer 3: bufB -> bufA ----
    aggregate_kernel<<<aggBlocks, 256, 0, stream>>>(bufB, rowptr, csr, aggrN);
    combine_kernel<<<combBlocks, 256, 0, stream>>>(bufB, aggrN, W3l, b3l, W3r, bufA);

    // ---- global mean pool ----
    hipMemsetAsync(gs, 0, (N_GRAPHS * H + N_GRAPHS) * sizeof(float), stream);
    pool_cnt_kernel<<<(N_NODES + 255) / 256, 256, 0, stream>>>(batch, gc);
    pool_sum_kernel<<<2048, 256, 0, stream>>>(bufA, batch, gs);

    // ---- MLP head ----
    mlp_kernel<<<N_GRAPHS, 64, 0, stream>>>(gs, gc, fc1_w, fc1_b, fc2_w, fc2_b, out);
}

// Round 3
// 457.159 us; speedup vs baseline: 3.2185x; 1.1672x over previous
//
#include <hip/hip_runtime.h>
#include <hip/hip_bf16.h>

#define N_NODES 50000
#define N_EDGES 800000
#define N_GRAPHS 500
#define H 90

typedef __attribute__((ext_vector_type(8))) short bf16x8;
typedef __attribute__((ext_vector_type(8))) unsigned short u16x8;
typedef __attribute__((ext_vector_type(4))) float f32x4;

// pack float -> (bf16_hi | bf16_lo) u32; hi+lo reconstructs v to ~2^-18 rel
__device__ __forceinline__ unsigned pack2(float v) {
    unsigned u = __float_as_uint(v);
    unsigned hi = (u + 0x7fffu + ((u >> 16) & 1u)) & 0xffff0000u;   // RNE bf16
    float lo = v - __uint_as_float(hi);
    unsigned ul = __float_as_uint(lo);
    unsigned lb = (ul + 0x7fffu + ((ul >> 16) & 1u)) >> 16;
    return hi | lb;
}

__device__ __forceinline__ float unpack2(unsigned p) {
    return __uint_as_float(p & 0xffff0000u) + __uint_as_float(p << 16);
}

// ================= input conversion =================
__global__ __launch_bounds__(256) void convert_x_kernel(const float* __restrict__ x,
                                                        unsigned* __restrict__ xp) {
    const int total = N_NODES * H;
    int stride = gridDim.x * blockDim.x;
    for (int i = blockIdx.x * blockDim.x + threadIdx.x; i < total; i += stride)
        xp[i] = pack2(x[i]);
}

// W [90][90] fp32 -> Whi/Wlo bf16 [96][96] zero-padded; 6 matrices via blockIdx.y
__global__ __launch_bounds__(256) void convert_w_kernel(const float* __restrict__ w0,
                                                        const float* __restrict__ w1,
                                                        const float* __restrict__ w2,
                                                        const float* __restrict__ w3,
                                                        const float* __restrict__ w4,
                                                        const float* __restrict__ w5,
                                                        unsigned short* __restrict__ wbuf) {
    int m = blockIdx.y;
    const float* src = (m == 0) ? w0 : (m == 1) ? w1 : (m == 2) ? w2
                     : (m == 3) ? w3 : (m == 4) ? w4 : w5;
    unsigned short* dhi = wbuf + (size_t)m * 2 * 96 * 96;
    unsigned short* dlo = dhi + 96 * 96;
    int idx = blockIdx.x * blockDim.x + threadIdx.x;
    if (idx < 96 * 96) {
        int r = idx / 96, c = idx - r * 96;
        float v = (r < H && c < H) ? src[r * H + c] : 0.0f;
        unsigned p = pack2(v);
        dhi[idx] = (unsigned short)(p >> 16);
        dlo[idx] = (unsigned short)(p & 0xffffu);
    }
}

// ================= CSR build =================
__global__ __launch_bounds__(256) void deg_kernel(const int* __restrict__ dst,
                                                  int* __restrict__ deg) {
    int e = blockIdx.x * blockDim.x + threadIdx.x;
    if (e < N_EDGES) atomicAdd(&deg[dst[e]], 1);
}

#define SCAN_B 512
#define NSB ((N_NODES + SCAN_B - 1) / SCAN_B)   // 98
__global__ __launch_bounds__(SCAN_B) void scan1_kernel(const int* __restrict__ deg,
                                                       int* __restrict__ rowloc,
                                                       int* __restrict__ bsum) {
    __shared__ int s[SCAN_B];
    int t = threadIdx.x;
    int i = blockIdx.x * SCAN_B + t;
    int v = (i < N_NODES) ? deg[i] : 0;
    s[t] = v;
    __syncthreads();
    for (int off = 1; off < SCAN_B; off <<= 1) {
        int u = (t >= off) ? s[t - off] : 0;
        __syncthreads();
        s[t] += u;
        __syncthreads();
    }
    if (i < N_NODES) rowloc[i] = s[t] - v;
    if (t == SCAN_B - 1) bsum[blockIdx.x] = s[t];
}

__global__ __launch_bounds__(128) void scan2_kernel(const int* __restrict__ bsum,
                                                    int* __restrict__ boff) {
    __shared__ int s[128];
    int t = threadIdx.x;
    int v = (t < NSB) ? bsum[t] : 0;
    s[t] = v;
    __syncthreads();
    for (int off = 1; off < 128; off <<= 1) {
        int u = (t >= off) ? s[t - off] : 0;
        __syncthreads();
        s[t] += u;
        __syncthreads();
    }
    boff[t] = s[t] - v;
}

__global__ __launch_bounds__(256) void scan3_kernel(const int* __restrict__ rowloc,
                                                    const int* __restrict__ boff,
                                                    int* __restrict__ rowptr) {
    int i = blockIdx.x * blockDim.x + threadIdx.x;
    if (i < N_NODES) rowptr[i] = rowloc[i] + boff[i / SCAN_B];
    else if (i == N_NODES) rowptr[i] = N_EDGES;
}

__global__ __launch_bounds__(256) void fill_kernel(const int* __restrict__ src,
                                                   const int* __restrict__ dst,
                                                   const int* __restrict__ rowptr,
                                                   int* __restrict__ fill,
                                                   int* __restrict__ csr) {
    int e = blockIdx.x * blockDim.x + threadIdx.x;
    if (e < N_EDGES) {
        int d = dst[e];
        int p = atomicAdd(&fill[d], 1);
        csr[rowptr[d] + p] = src[e];
    }
}

// ================= gather-mean aggregation over packed activations =================
__global__ __launch_bounds__(256) void aggregate_kernel(const unsigned* __restrict__ xin,
                                                        const int* __restrict__ rowptr,
                                                        const int* __restrict__ csr,
                                                        unsigned* __restrict__ aggr) {
    int wv = threadIdx.x >> 6;
    int lane = threadIdx.x & 63;
    int n = blockIdx.x * 4 + wv;            // 12500*4 = 50000 exact
    int r0 = rowptr[n];
    int r1 = rowptr[n + 1];
    float a0 = 0.0f, a1 = 0.0f;
    bool hi = (lane < H - 64);              // lane < 26 handles k = 64+lane
    int j = r0;
    for (; j + 3 < r1; j += 4) {
        int s0 = csr[j], s1 = csr[j + 1], s2 = csr[j + 2], s3 = csr[j + 3];
        const unsigned* p0 = xin + s0 * H;
        const unsigned* p1 = xin + s1 * H;
        const unsigned* p2 = xin + s2 * H;
        const unsigned* p3 = xin + s3 * H;
        unsigned v0 = p0[lane], v1 = p1[lane], v2 = p2[lane], v3 = p3[lane];
        a0 += unpack2(v0) + unpack2(v1) + unpack2(v2) + unpack2(v3);
        if (hi) {
            unsigned w0 = p0[64 + lane], w1 = p1[64 + lane];
            unsigned w2 = p2[64 + lane], w3 = p3[64 + lane];
            a1 += unpack2(w0) + unpack2(w1) + unpack2(w2) + unpack2(w3);
        }
    }
    for (; j < r1; ++j) {
        const unsigned* p0 = xin + csr[j] * H;
        a0 += unpack2(p0[lane]);
        if (hi) a1 += unpack2(p0[64 + lane]);
    }
    float inv = 1.0f / (float)max(r1 - r0, 1);
    aggr[n * H + lane] = pack2(a0 * inv);
    if (hi) aggr[n * H + 64 + lane] = pack2(a1 * inv);
}

// ================= combine via split-bf16 MFMA =================
// out[n][h] = relu(b[h] + aggr[n]·Wl[h] + x[n]·Wr[h]), 3-term split per product.
// Block: 256 thr (4 waves), 32 nodes x 96 h; wave tile 16 nodes x 48 h (3 C-tiles).
#define KP 104   // LDS k-stride (bf16): 52 dwords -> 8 start banks -> 2-way (free)
__global__ __launch_bounds__(256) void combine_kernel(const unsigned* __restrict__ xp,
                                                      const unsigned* __restrict__ ap,
                                                      const unsigned short* __restrict__ whl,
                                                      const unsigned short* __restrict__ wll,
                                                      const unsigned short* __restrict__ whr,
                                                      const unsigned short* __restrict__ wlr,
                                                      const float* __restrict__ bias,
                                                      unsigned* __restrict__ outp) {
    __shared__ __align__(16) unsigned short sAh[32][KP];
    __shared__ __align__(16) unsigned short sAl[32][KP];
    __shared__ __align__(16) unsigned short sWh[96][KP];
    __shared__ __align__(16) unsigned short sWl[96][KP];
    __shared__ float sb[96];

    const int tid = threadIdx.x;
    const int lane = tid & 63;
    const int wv = tid >> 6;
    const int ns = wv >> 1;      // node stripe 0..1
    const int hs = wv & 1;       // h stripe 0..1
    const int node0 = blockIdx.x * 32;

    if (tid < 96) sb[tid] = (tid < H) ? bias[tid] : 0.0f;

    f32x4 acc[3] = {};

    for (int pass = 0; pass < 2; ++pass) {
        const unsigned* Asrc = pass ? xp : ap;
        const unsigned short* wh = pass ? whr : whl;
        const unsigned short* wl = pass ? wlr : wll;
        __syncthreads();   // previous pass k-loop reads complete
        // stage A (packed u32 -> hi/lo bf16 tiles)
        for (int idx = tid; idx < 32 * H; idx += 256) {
            int r = idx / H, c = idx - r * H;
            int node = node0 + r;
            unsigned g = (node < N_NODES) ? Asrc[node * H + c] : 0u;
            sAh[r][c] = (unsigned short)(g >> 16);
            sAl[r][c] = (unsigned short)(g & 0xffffu);
        }
        for (int idx = tid; idx < 32 * (KP - H); idx += 256) {
            int r = idx / (KP - H), c = H + (idx - r * (KP - H));
            sAh[r][c] = 0;
            sAl[r][c] = 0;
        }
        // stage W (pre-padded bf16 [96][96] -> LDS, 16B chunks; chunk 12 zeros 96..103)
        for (int idx = tid; idx < 96 * 13; idx += 256) {
            int r = idx / 13, c8 = idx - r * 13;
            u16x8 zh = {}, zl = {};
            if (c8 < 12) {
                zh = *reinterpret_cast<const u16x8*>(wh + r * 96 + c8 * 8);
                zl = *reinterpret_cast<const u16x8*>(wl + r * 96 + c8 * 8);
            }
            *reinterpret_cast<u16x8*>(&sWh[r][c8 * 8]) = zh;
            *reinterpret_cast<u16x8*>(&sWl[r][c8 * 8]) = zl;
        }
        __syncthreads();

        const int arow = ns * 16 + (lane & 15);
#pragma unroll
        for (int ks = 0; ks < 3; ++ks) {
            const int koff = ks * 32 + ((lane >> 4) << 3);
            bf16x8 Ah = *reinterpret_cast<const bf16x8*>(&sAh[arow][koff]);
            bf16x8 Al = *reinterpret_cast<const bf16x8*>(&sAl[arow][koff]);
#pragma unroll
            for (int t = 0; t < 3; ++t) {
                const int wrow = hs * 48 + t * 16 + (lane & 15);
                bf16x8 Bh = *reinterpret_cast<const bf16x8*>(&sWh[wrow][koff]);
                bf16x8 Bl = *reinterpret_cast<const bf16x8*>(&sWl[wrow][koff]);
                acc[t] = __builtin_amdgcn_mfma_f32_16x16x32_bf16(Ah, Bh, acc[t], 0, 0, 0);
                acc[t] = __builtin_amdgcn_mfma_f32_16x16x32_bf16(Al, Bh, acc[t], 0, 0, 0);
                acc[t] = __builtin_amdgcn_mfma_f32_16x16x32_bf16(Ah, Bl, acc[t], 0, 0, 0);
            }
        }
    }

    // epilogue: C col(h)=lane&15, row(node)=(lane>>4)*4+reg
#pragma unroll
    for (int t = 0; t < 3; ++t) {
        int h = hs * 48 + t * 16 + (lane & 15);
#pragma unroll
        for (int r = 0; r < 4; ++r) {
            int node = node0 + ns * 16 + ((lane >> 4) << 2) + r;
            if (h < H && node < N_NODES) {
                float v = acc[t][r] + sb[h];
                outp[node * H + h] = pack2(fmaxf(v, 0.0f));
            }
        }
    }
}

// ================= pooling =================
__global__ __launch_bounds__(256) void pool_cnt_kernel(const int* __restrict__ batch,
                                                       float* __restrict__ gc) {
    int i = blockIdx.x * blockDim.x + threadIdx.x;
    if (i < N_NODES) atomicAdd(&gc[batch[i]], 1.0f);
}

__global__ __launch_bounds__(256) void pool_sum_kernel(const unsigned* __restrict__ h3,
                                                       const int* __restrict__ batch,
                                                       float* __restrict__ gs) {
    const int total = N_NODES * H;
    int stride = gridDim.x * blockDim.x;
    for (int idx = blockIdx.x * blockDim.x + threadIdx.x; idx < total; idx += stride) {
        int i = idx / H;
        int h = idx - i * H;
        int g = batch[i];
        atomicAdd(&gs[g * H + h], unpack2(h3[idx]));
    }
}

// ================= MLP head =================
__global__ __launch_bounds__(64) void mlp_kernel(const float* __restrict__ gs,
                                                 const float* __restrict__ gc,
                                                 const float* __restrict__ fc1_w,
                                                 const float* __restrict__ fc1_b,
                                                 const float* __restrict__ fc2_w,
                                                 const float* __restrict__ fc2_b,
                                                 float* __restrict__ out) {
    int g = blockIdx.x;
    int t = threadIdx.x;
    __shared__ float h4[H];
    float inv = 1.0f / fmaxf(gc[g], 1.0f);
    for (int k = t; k < H; k += 64) h4[k] = gs[g * H + k] * inv;
    __syncthreads();
    float v = 0.0f;
    if (t < 32) {
        float acc = fc1_b[t];
#pragma unroll 6
        for (int k = 0; k < H; ++k) acc += h4[k] * fc1_w[t * H + k];
        v = fmaxf(acc, 0.0f) * fc2_w[t];
    }
    for (int off = 16; off; off >>= 1) v += __shfl_down(v, off, 32);
    if (t == 0) out[g] = v + fc2_b[0];
}

extern "C" void kernel_launch(void* const* d_in, const int* in_sizes, int n_in,
                              void* d_out, int out_size, void* d_ws, size_t ws_size,
                              hipStream_t stream) {
    const float* x     = (const float*)d_in[0];
    const int*   ei    = (const int*)d_in[1];
    const int*   batch = (const int*)d_in[2];
    const float* W1l = (const float*)d_in[3];
    const float* b1l = (const float*)d_in[4];
    const float* W1r = (const float*)d_in[5];
    const float* W2l = (const float*)d_in[6];
    const float* b2l = (const float*)d_in[7];
    const float* W2r = (const float*)d_in[8];
    const float* W3l = (const float*)d_in[9];
    const float* b3l = (const float*)d_in[10];
    const float* W3r = (const float*)d_in[11];
    const float* fc1_w = (const float*)d_in[12];
    const float* fc1_b = (const float*)d_in[13];
    const float* fc2_w = (const float*)d_in[14];
    const float* fc2_b = (const float*)d_in[15];

    const int* src = ei;
    const int* dst = ei + N_EDGES;

    // ---- workspace layout (bytes; total ~57.8 MB) ----
    char* ws = (char*)d_ws;
    unsigned* P0  = (unsigned*)(ws);                          // [N][H] u32  18.0 MB
    unsigned* P1  = P0 + (size_t)N_NODES * H;                 // 18.0 MB
    unsigned* AGG = P1 + (size_t)N_NODES * H;                 // 18.0 MB
    int* csr    = (int*)(AGG + (size_t)N_NODES * H);          // 3.2 MB
    int* rowptr = csr + N_EDGES;                              // 200 KB
    unsigned short* wbuf = (unsigned short*)(rowptr + N_NODES + 1);  // 6*2*96*96 bf16
    float* gs = (float*)(wbuf + 6 * 2 * 96 * 96);             // N_GRAPHS*H
    float* gc = gs + N_GRAPHS * H;                            // N_GRAPHS

    // CSR-build temporaries aliased into AGG (dead before first aggregate)
    int* deg    = (int*)AGG;
    int* fil    = deg + N_NODES;
    int* rowloc = fil + N_NODES;
    int* bsum   = rowloc + N_NODES;
    int* boff   = bsum + 128;

    const unsigned short* w1lh = wbuf + 0 * 2 * 96 * 96;
    const unsigned short* w1ll = w1lh + 96 * 96;
    const unsigned short* w1rh = wbuf + 1 * 2 * 96 * 96;
    const unsigned short* w1rl = w1rh + 96 * 96;
    const unsigned short* w2lh = wbuf + 2 * 2 * 96 * 96;
    const unsigned short* w2ll = w2lh + 96 * 96;
    const unsigned short* w2rh = wbuf + 3 * 2 * 96 * 96;
    const unsigned short* w2rl = w2rh + 96 * 96;
    const unsigned short* w3lh = wbuf + 4 * 2 * 96 * 96;
    const unsigned short* w3ll = w3lh + 96 * 96;
    const unsigned short* w3rh = wbuf + 5 * 2 * 96 * 96;
    const unsigned short* w3rl = w3rh + 96 * 96;

    float* out = (float*)d_out;

    const int edgeBlocks = (N_EDGES + 255) / 256;
    const int combBlocks = (N_NODES + 31) / 32;     // 1563
    const int aggBlocks  = N_NODES / 4;             // 12500

    // ---- weight/input conversion ----
    convert_w_kernel<<<dim3(36, 6), 256, 0, stream>>>(W1l, W1r, W2l, W2r, W3l, W3r, wbuf);
    convert_x_kernel<<<2048, 256, 0, stream>>>(x, P0);

    // ---- CSR build ----
    hipMemsetAsync(deg, 0, 2 * N_NODES * sizeof(int), stream);  // deg + fil
    deg_kernel<<<edgeBlocks, 256, 0, stream>>>(dst, deg);
    scan1_kernel<<<NSB, SCAN_B, 0, stream>>>(deg, rowloc, bsum);
    scan2_kernel<<<1, 128, 0, stream>>>(bsum, boff);
    scan3_kernel<<<(N_NODES + 256) / 256, 256, 0, stream>>>(rowloc, boff, rowptr);
    fill_kernel<<<edgeBlocks, 256, 0, stream>>>(src, dst, rowptr, fil, csr);

    // ---- layer 1: P0 -> P1 ----
    aggregate_kernel<<<aggBlocks, 256, 0, stream>>>(P0, rowptr, csr, AGG);
    combine_kernel<<<combBlocks, 256, 0, stream>>>(P0, AGG, w1lh, w1ll, w1rh, w1rl, b1l, P1);

    // ---- layer 2: P1 -> P0 ----
    aggregate_kernel<<<aggBlocks, 256, 0, stream>>>(P1, rowptr, csr, AGG);
    combine_kernel<<<combBlocks, 256, 0, stream>>>(P1, AGG, w2lh, w2ll, w2rh, w2rl, b2l, P0);

    // ---- layer 3: P0 -> P1 ----
    aggregate_kernel<<<aggBlocks, 256, 0, stream>>>(P0, rowptr, csr, AGG);
    combine_kernel<<<combBlocks, 256, 0, stream>>>(P0, AGG, w3lh, w3ll, w3rh, w3rl, b3l, P1);

    // ---- global mean pool ----
    hipMemsetAsync(gs, 0, (N_GRAPHS * H + N_GRAPHS) * sizeof(float), stream);
    pool_cnt_kernel<<<(N_NODES + 255) / 256, 256, 0, stream>>>(batch, gc);
    pool_sum_kernel<<<2048, 256, 0, stream>>>(P1, batch, gs);

    // ---- MLP head ----
    mlp_kernel<<<N_GRAPHS, 64, 0, stream>>>(gs, gc, fc1_w, fc1_b, fc2_w, fc2_b, out);
}

// Round 4
// 404.594 us; speedup vs baseline: 3.6367x; 1.1299x over previous
//
#include <hip/hip_runtime.h>
#include <hip/hip_bf16.h>

#define N_NODES 50000
#define N_EDGES 800000
#define N_GRAPHS 500
#define H 90
#define KP 96          // LDS row length in u16 units (192 B), XOR-swizzled
#define SGROWS 6

typedef __attribute__((ext_vector_type(8))) short bf16x8;
typedef __attribute__((ext_vector_type(8))) unsigned short u16x8;
typedef __attribute__((ext_vector_type(4))) float f32x4;

// split float -> bf16 hi + bf16 residual lo (RNE); hi+lo ~= v to 2^-18 rel
__device__ __forceinline__ void pack_split(float v, unsigned short& h16, unsigned short& l16) {
    unsigned u = __float_as_uint(v);
    unsigned hi = (u + 0x7fffu + ((u >> 16) & 1u)) & 0xffff0000u;
    float lo = v - __uint_as_float(hi);
    unsigned ul = __float_as_uint(lo);
    h16 = (unsigned short)(hi >> 16);
    l16 = (unsigned short)((ul + 0x7fffu + ((ul >> 16) & 1u)) >> 16);
}
__device__ __forceinline__ float bf2f(unsigned short h) {
    return __uint_as_float(((unsigned)h) << 16);
}
// XOR-swizzled byte offset within an LDS tile of row stride KP*2 = 192 B
__device__ __forceinline__ int swzb(int row, int byteInRow) {
    return (row * (KP * 2) + byteInRow) ^ ((row & 7) << 4);
}

// ================= weight conversion: [90][90] f32 -> hi/lo bf16 [96][96] =================
__global__ __launch_bounds__(256) void convert_w_kernel(const float* __restrict__ w0,
                                                        const float* __restrict__ w1,
                                                        const float* __restrict__ w2,
                                                        const float* __restrict__ w3,
                                                        const float* __restrict__ w4,
                                                        const float* __restrict__ w5,
                                                        unsigned short* __restrict__ wbuf) {
    int m = blockIdx.y;
    const float* src = (m == 0) ? w0 : (m == 1) ? w1 : (m == 2) ? w2
                     : (m == 3) ? w3 : (m == 4) ? w4 : w5;
    unsigned short* dhi = wbuf + (size_t)m * 2 * 96 * 96;
    unsigned short* dlo = dhi + 96 * 96;
    int idx = blockIdx.x * blockDim.x + threadIdx.x;
    if (idx < 96 * 96) {
        int r = idx / 96, c = idx - r * 96;
        float v = (r < H && c < H) ? src[r * H + c] : 0.0f;
        unsigned short h16, l16;
        pack_split(v, h16, l16);
        dhi[idx] = h16;
        dlo[idx] = l16;
    }
}

// ================= CSR build =================
__global__ __launch_bounds__(256) void deg_kernel(const int* __restrict__ dst,
                                                  int* __restrict__ deg) {
    int e = blockIdx.x * blockDim.x + threadIdx.x;
    if (e < N_EDGES) atomicAdd(&deg[dst[e]], 1);
}

#define SCAN_B 512
#define NSB ((N_NODES + SCAN_B - 1) / SCAN_B)   // 98
__global__ __launch_bounds__(SCAN_B) void scan1_kernel(const int* __restrict__ deg,
                                                       int* __restrict__ rowloc,
                                                       int* __restrict__ bsum) {
    __shared__ int s[SCAN_B];
    int t = threadIdx.x;
    int i = blockIdx.x * SCAN_B + t;
    int v = (i < N_NODES) ? deg[i] : 0;
    s[t] = v;
    __syncthreads();
    for (int off = 1; off < SCAN_B; off <<= 1) {
        int u = (t >= off) ? s[t - off] : 0;
        __syncthreads();
        s[t] += u;
        __syncthreads();
    }
    if (i < N_NODES) rowloc[i] = s[t] - v;
    if (t == SCAN_B - 1) bsum[blockIdx.x] = s[t];
}

__global__ __launch_bounds__(128) void scan2_kernel(const int* __restrict__ bsum,
                                                    int* __restrict__ boff) {
    __shared__ int s[128];
    int t = threadIdx.x;
    int v = (t < NSB) ? bsum[t] : 0;
    s[t] = v;
    __syncthreads();
    for (int off = 1; off < 128; off <<= 1) {
        int u = (t >= off) ? s[t - off] : 0;
        __syncthreads();
        s[t] += u;
        __syncthreads();
    }
    boff[t] = s[t] - v;
}

__global__ __launch_bounds__(256) void scan3_kernel(const int* __restrict__ rowloc,
                                                    const int* __restrict__ boff,
                                                    int* __restrict__ rowptr) {
    int i = blockIdx.x * blockDim.x + threadIdx.x;
    if (i < N_NODES) rowptr[i] = rowloc[i] + boff[i / SCAN_B];
    else if (i == N_NODES) rowptr[i] = N_EDGES;
}

__global__ __launch_bounds__(256) void fill_kernel(const int* __restrict__ src,
                                                   const int* __restrict__ dst,
                                                   const int* __restrict__ rowptr,
                                                   int* __restrict__ fill,
                                                   int* __restrict__ csr) {
    int e = blockIdx.x * blockDim.x + threadIdx.x;
    if (e < N_EDGES) {
        int d = dst[e];
        int p = atomicAdd(&fill[d], 1);
        csr[rowptr[d] + p] = src[e];
    }
}

// ================= aggregation (wave per node) =================
// layer 1: exact fp32 gather from x
__global__ __launch_bounds__(256) void aggregate_f32_kernel(const float* __restrict__ xin,
                                                            const int* __restrict__ rowptr,
                                                            const int* __restrict__ csr,
                                                            unsigned short* __restrict__ ahi,
                                                            unsigned short* __restrict__ alo) {
    int wv = threadIdx.x >> 6;
    int lane = threadIdx.x & 63;
    int n = blockIdx.x * 4 + wv;           // 12500*4 = 50000 exact
    int r0 = rowptr[n], r1 = rowptr[n + 1];
    float a0 = 0.0f, a1 = 0.0f;
    bool hi = lane < (H - 64);
    int j = r0;
    for (; j + 3 < r1; j += 4) {
        const float* p0 = xin + (size_t)csr[j] * H;
        const float* p1 = xin + (size_t)csr[j + 1] * H;
        const float* p2 = xin + (size_t)csr[j + 2] * H;
        const float* p3 = xin + (size_t)csr[j + 3] * H;
        a0 += p0[lane] + p1[lane] + p2[lane] + p3[lane];
        if (hi) a1 += p0[64 + lane] + p1[64 + lane] + p2[64 + lane] + p3[64 + lane];
    }
    for (; j < r1; ++j) {
        const float* p = xin + (size_t)csr[j] * H;
        a0 += p[lane];
        if (hi) a1 += p[64 + lane];
    }
    float inv = 1.0f / (float)max(r1 - r0, 1);
    unsigned short h16, l16;
    pack_split(a0 * inv, h16, l16);
    ahi[(size_t)n * H + lane] = h16;
    alo[(size_t)n * H + lane] = l16;
    if (hi) {
        pack_split(a1 * inv, h16, l16);
        ahi[(size_t)n * H + 64 + lane] = h16;
        alo[(size_t)n * H + 64 + lane] = l16;
    }
}

// layers 2,3: hi-plane-only gather (halves gather bytes)
__global__ __launch_bounds__(256) void aggregate_hi_kernel(const unsigned short* __restrict__ xhi,
                                                           const int* __restrict__ rowptr,
                                                           const int* __restrict__ csr,
                                                           unsigned short* __restrict__ ahi,
                                                           unsigned short* __restrict__ alo) {
    int wv = threadIdx.x >> 6;
    int lane = threadIdx.x & 63;
    int n = blockIdx.x * 4 + wv;
    int r0 = rowptr[n], r1 = rowptr[n + 1];
    float a0 = 0.0f, a1 = 0.0f;
    bool hi = lane < (H - 64);
    int j = r0;
    for (; j + 3 < r1; j += 4) {
        const unsigned short* p0 = xhi + (size_t)csr[j] * H;
        const unsigned short* p1 = xhi + (size_t)csr[j + 1] * H;
        const unsigned short* p2 = xhi + (size_t)csr[j + 2] * H;
        const unsigned short* p3 = xhi + (size_t)csr[j + 3] * H;
        a0 += bf2f(p0[lane]) + bf2f(p1[lane]) + bf2f(p2[lane]) + bf2f(p3[lane]);
        if (hi) a1 += bf2f(p0[64 + lane]) + bf2f(p1[64 + lane]) +
                      bf2f(p2[64 + lane]) + bf2f(p3[64 + lane]);
    }
    for (; j < r1; ++j) {
        const unsigned short* p = xhi + (size_t)csr[j] * H;
        a0 += bf2f(p[lane]);
        if (hi) a1 += bf2f(p[64 + lane]);
    }
    float inv = 1.0f / (float)max(r1 - r0, 1);
    unsigned short h16, l16;
    pack_split(a0 * inv, h16, l16);
    ahi[(size_t)n * H + lane] = h16;
    alo[(size_t)n * H + lane] = l16;
    if (hi) {
        pack_split(a1 * inv, h16, l16);
        ahi[(size_t)n * H + 64 + lane] = h16;
        alo[(size_t)n * H + 64 + lane] = l16;
    }
}

// ================= combine via split-bf16 MFMA =================
// Block: 256 thr (4 waves), 64 nodes x 96 h; wave = 16 nodes x 96 h (6 C tiles).
// MODE 0: pass1 A from raw fp32 x, plane output.
// MODE 1: plane input, plane output.
// MODE 2: plane input, fused global-mean-pool (atomics into gs).
template<int MODE>
__global__ __launch_bounds__(256) void combine_kernel(
        const unsigned short* __restrict__ aghi, const unsigned short* __restrict__ aglo,
        const float* __restrict__ xraw,
        const unsigned short* __restrict__ xhi, const unsigned short* __restrict__ xlo,
        const unsigned short* __restrict__ wl,   // hi plane then lo plane (96*96 each)
        const unsigned short* __restrict__ wr,
        const float* __restrict__ bias,
        unsigned short* __restrict__ ohi, unsigned short* __restrict__ olo,
        const int* __restrict__ batch, float* __restrict__ gs) {
    __shared__ unsigned short sAh[64 * KP], sAl[64 * KP];
    __shared__ unsigned short sWh[96 * KP], sWl[96 * KP];
    __shared__ float sb[96];
    __shared__ float SG[SGROWS * 96];

    const int tid = threadIdx.x;
    const int lane = tid & 63;
    const int wv = tid >> 6;
    const int node0 = blockIdx.x * 64;

    if (tid < 96) sb[tid] = (tid < H) ? bias[tid] : 0.0f;
    if (MODE == 2)
        for (int i = tid; i < SGROWS * 96; i += 256) SG[i] = 0.0f;

    f32x4 acc[6] = {};

    for (int pass = 0; pass < 2; ++pass) {
        __syncthreads();   // previous pass LDS reads complete
        // ---- stage A ----
        if (pass == 1 && MODE == 0) {
            for (int idx = tid; idx < 64 * 45; idx += 256) {
                int r = idx / 45, c2 = idx - r * 45;
                int node = node0 + r;
                float2 f = make_float2(0.0f, 0.0f);
                if (node < N_NODES)
                    f = *reinterpret_cast<const float2*>(xraw + (size_t)node * H + c2 * 2);
                unsigned short hx, lx, hy, ly;
                pack_split(f.x, hx, lx);
                pack_split(f.y, hy, ly);
                *(unsigned*)((char*)sAh + swzb(r, c2 * 4)) = (unsigned)hx | ((unsigned)hy << 16);
                *(unsigned*)((char*)sAl + swzb(r, c2 * 4)) = (unsigned)lx | ((unsigned)ly << 16);
            }
        } else {
            const unsigned short* ph = pass ? xhi : aghi;
            const unsigned short* pl = pass ? xlo : aglo;
            for (int idx = tid; idx < 64 * 45; idx += 256) {
                int r = idx / 45, c2 = idx - r * 45;
                int node = node0 + r;
                unsigned vh = 0, vlv = 0;
                if (node < N_NODES) {
                    vh  = *(const unsigned*)((const char*)ph + (size_t)node * 180 + c2 * 4);
                    vlv = *(const unsigned*)((const char*)pl + (size_t)node * 180 + c2 * 4);
                }
                *(unsigned*)((char*)sAh + swzb(r, c2 * 4)) = vh;
                *(unsigned*)((char*)sAl + swzb(r, c2 * 4)) = vlv;
            }
        }
        // zero A cols 90..95 (3 u32 per row)
        for (int idx = tid; idx < 64 * 3; idx += 256) {
            int r = idx / 3, c2 = 45 + (idx - r * 3);
            *(unsigned*)((char*)sAh + swzb(r, c2 * 4)) = 0u;
            *(unsigned*)((char*)sAl + swzb(r, c2 * 4)) = 0u;
        }
        // ---- stage W (pre-padded [96][96], rows 90..95 already zero) ----
        {
            const unsigned short* w = pass ? wr : wl;
            const unsigned short* whi = w;
            const unsigned short* wlo = w + 96 * 96;
            for (int idx = tid; idx < 96 * 12; idx += 256) {
                int r = idx / 12, c8 = idx - r * 12;
                u16x8 a = *reinterpret_cast<const u16x8*>(whi + r * 96 + c8 * 8);
                u16x8 b = *reinterpret_cast<const u16x8*>(wlo + r * 96 + c8 * 8);
                *(u16x8*)((char*)sWh + swzb(r, c8 * 16)) = a;
                *(u16x8*)((char*)sWl + swzb(r, c8 * 16)) = b;
            }
        }
        __syncthreads();

        // ---- MFMA ----
        const int arow = wv * 16 + (lane & 15);
        const int kbyte0 = ((lane >> 4) << 3) * 2;
#pragma unroll
        for (int ks = 0; ks < 3; ++ks) {
            int kb = ks * 64 + kbyte0;
            bf16x8 Ah = *(const bf16x8*)((const char*)sAh + swzb(arow, kb));
            bf16x8 Al = *(const bf16x8*)((const char*)sAl + swzb(arow, kb));
#pragma unroll
            for (int t = 0; t < 6; ++t) {
                int wrow = t * 16 + (lane & 15);
                bf16x8 Bh = *(const bf16x8*)((const char*)sWh + swzb(wrow, kb));
                bf16x8 Bl = *(const bf16x8*)((const char*)sWl + swzb(wrow, kb));
                acc[t] = __builtin_amdgcn_mfma_f32_16x16x32_bf16(Ah, Bh, acc[t], 0, 0, 0);
                acc[t] = __builtin_amdgcn_mfma_f32_16x16x32_bf16(Al, Bh, acc[t], 0, 0, 0);
                acc[t] = __builtin_amdgcn_mfma_f32_16x16x32_bf16(Ah, Bl, acc[t], 0, 0, 0);
            }
        }
    }

    // ---- epilogue: C col(h)=lane&15, row(node)=(lane>>4)*4+reg ----
    int gmin = 0;
    if (MODE == 2) gmin = batch[node0];
#pragma unroll
    for (int t = 0; t < 6; ++t) {
        int h = t * 16 + (lane & 15);
        if (h >= H) continue;
#pragma unroll
        for (int r = 0; r < 4; ++r) {
            int node = node0 + wv * 16 + ((lane >> 4) << 2) + r;
            if (node >= N_NODES) continue;
            float v = fmaxf(acc[t][r] + sb[h], 0.0f);
            if (MODE == 2) {
                int g = batch[node];
                int gl = g - gmin;
                if (gl < SGROWS) atomicAdd(&SG[gl * 96 + h], v);
                else atomicAdd(&gs[g * H + h], v);
            } else {
                unsigned short h16, l16;
                pack_split(v, h16, l16);
                ohi[(size_t)node * H + h] = h16;
                olo[(size_t)node * H + h] = l16;
            }
        }
    }
    if (MODE == 2) {
        __syncthreads();
        for (int idx = tid; idx < SGROWS * 96; idx += 256) {
            int r = idx / 96, c = idx - r * 96;
            float s = SG[idx];
            if (c < H && s != 0.0f) atomicAdd(&gs[(gmin + r) * H + c], s);
        }
    }
}

// ================= pooling counts =================
__global__ __launch_bounds__(256) void pool_cnt_kernel(const int* __restrict__ batch,
                                                       float* __restrict__ gc) {
    int i = blockIdx.x * blockDim.x + threadIdx.x;
    if (i < N_NODES) atomicAdd(&gc[batch[i]], 1.0f);
}

// ================= MLP head =================
__global__ __launch_bounds__(64) void mlp_kernel(const float* __restrict__ gs,
                                                 const float* __restrict__ gc,
                                                 const float* __restrict__ fc1_w,
                                                 const float* __restrict__ fc1_b,
                                                 const float* __restrict__ fc2_w,
                                                 const float* __restrict__ fc2_b,
                                                 float* __restrict__ out) {
    int g = blockIdx.x;
    int t = threadIdx.x;
    __shared__ float h4[H];
    float inv = 1.0f / fmaxf(gc[g], 1.0f);
    for (int k = t; k < H; k += 64) h4[k] = gs[g * H + k] * inv;
    __syncthreads();
    float v = 0.0f;
    if (t < 32) {
        float acc = fc1_b[t];
#pragma unroll 6
        for (int k = 0; k < H; ++k) acc += h4[k] * fc1_w[t * H + k];
        v = fmaxf(acc, 0.0f) * fc2_w[t];
    }
    for (int off = 16; off; off >>= 1) v += __shfl_down(v, off, 32);
    if (t == 0) out[g] = v + fc2_b[0];
}

extern "C" void kernel_launch(void* const* d_in, const int* in_sizes, int n_in,
                              void* d_out, int out_size, void* d_ws, size_t ws_size,
                              hipStream_t stream) {
    const float* x     = (const float*)d_in[0];
    const int*   ei    = (const int*)d_in[1];
    const int*   batch = (const int*)d_in[2];
    const float* W1l = (const float*)d_in[3];
    const float* b1l = (const float*)d_in[4];
    const float* W1r = (const float*)d_in[5];
    const float* W2l = (const float*)d_in[6];
    const float* b2l = (const float*)d_in[7];
    const float* W2r = (const float*)d_in[8];
    const float* W3l = (const float*)d_in[9];
    const float* b3l = (const float*)d_in[10];
    const float* W3r = (const float*)d_in[11];
    const float* fc1_w = (const float*)d_in[12];
    const float* fc1_b = (const float*)d_in[13];
    const float* fc2_w = (const float*)d_in[14];
    const float* fc2_b = (const float*)d_in[15];

    const int* src = ei;
    const int* dst = ei + N_EDGES;

    // ---- workspace layout (~57.8 MB) ----
    const size_t NH = (size_t)N_NODES * H;        // 4.5M
    unsigned short* P0h = (unsigned short*)d_ws;  // 9 MB each plane
    unsigned short* P0l = P0h + NH;
    unsigned short* P1h = P0l + NH;
    unsigned short* P1l = P1h + NH;
    unsigned short* AGh = P1l + NH;
    unsigned short* AGl = AGh + NH;
    int* csr    = (int*)(AGl + NH);               // 3.2 MB
    int* rowptr = csr + N_EDGES;                  // 200 KB
    unsigned short* wbuf = (unsigned short*)(rowptr + N_NODES + 1);  // 6*2*9216 u16
    float* gs = (float*)(wbuf + 6 * 2 * 96 * 96); // N_GRAPHS*H
    float* gc = gs + N_GRAPHS * H;                // N_GRAPHS

    // CSR-build temporaries aliased into AG planes (dead before first aggregate)
    int* deg    = (int*)AGh;
    int* fil    = deg + N_NODES;
    int* rowloc = fil + N_NODES;
    int* bsum   = rowloc + N_NODES;
    int* boff   = bsum + 128;

    const unsigned short* wb1l = wbuf + 0 * 2 * 96 * 96;
    const unsigned short* wb1r = wbuf + 1 * 2 * 96 * 96;
    const unsigned short* wb2l = wbuf + 2 * 2 * 96 * 96;
    const unsigned short* wb2r = wbuf + 3 * 2 * 96 * 96;
    const unsigned short* wb3l = wbuf + 4 * 2 * 96 * 96;
    const unsigned short* wb3r = wbuf + 5 * 2 * 96 * 96;

    float* out = (float*)d_out;

    const int edgeBlocks = (N_EDGES + 255) / 256;
    const int combBlocks = (N_NODES + 63) / 64;    // 782
    const int aggBlocks  = N_NODES / 4;            // 12500

    convert_w_kernel<<<dim3(36, 6), 256, 0, stream>>>(W1l, W1r, W2l, W2r, W3l, W3r, wbuf);

    // ---- CSR build ----
    hipMemsetAsync(deg, 0, 2 * N_NODES * sizeof(int), stream);  // deg + fil
    deg_kernel<<<edgeBlocks, 256, 0, stream>>>(dst, deg);
    scan1_kernel<<<NSB, SCAN_B, 0, stream>>>(deg, rowloc, bsum);
    scan2_kernel<<<1, 128, 0, stream>>>(bsum, boff);
    scan3_kernel<<<(N_NODES + 256) / 256, 256, 0, stream>>>(rowloc, boff, rowptr);
    fill_kernel<<<edgeBlocks, 256, 0, stream>>>(src, dst, rowptr, fil, csr);

    // pool setup (gs zeroed before fused layer-3 combine; gc counts)
    hipMemsetAsync(gs, 0, (N_GRAPHS * H + N_GRAPHS) * sizeof(float), stream);
    pool_cnt_kernel<<<(N_NODES + 255) / 256, 256, 0, stream>>>(batch, gc);

    // ---- layer 1: x (fp32) -> P0 planes ----
    aggregate_f32_kernel<<<aggBlocks, 256, 0, stream>>>(x, rowptr, csr, AGh, AGl);
    combine_kernel<0><<<combBlocks, 256, 0, stream>>>(AGh, AGl, x, nullptr, nullptr,
                                                      wb1l, wb1r, b1l, P0h, P0l,
                                                      nullptr, nullptr);
    // ---- layer 2: P0 -> P1 ----
    aggregate_hi_kernel<<<aggBlocks, 256, 0, stream>>>(P0h, rowptr, csr, AGh, AGl);
    combine_kernel<1><<<combBlocks, 256, 0, stream>>>(AGh, AGl, nullptr, P0h, P0l,
                                                      wb2l, wb2r, b2l, P1h, P1l,
                                                      nullptr, nullptr);
    // ---- layer 3: P1 -> fused pool into gs ----
    aggregate_hi_kernel<<<aggBlocks, 256, 0, stream>>>(P1h, rowptr, csr, AGh, AGl);
    combine_kernel<2><<<combBlocks, 256, 0, stream>>>(AGh, AGl, nullptr, P1h, P1l,
                                                      wb3l, wb3r, b3l, nullptr, nullptr,
                                                      batch, gs);

    // ---- MLP head ----
    mlp_kernel<<<N_GRAPHS, 64, 0, stream>>>(gs, gc, fc1_w, fc1_b, fc2_w, fc2_b, out);
}

// Round 5
// 373.830 us; speedup vs baseline: 3.9360x; 1.0823x over previous
//
#include <hip/hip_runtime.h>
#include <hip/hip_bf16.h>

#define N_NODES 50000
#define N_EDGES 800000
#define N_GRAPHS 500
#define H 90
#define PSTRIDE 96     // padded plane row stride (u16 elems) -> 192 B, 16B-aligned rows
#define SGROWS 8

typedef __attribute__((ext_vector_type(8))) short bf16x8;
typedef __attribute__((ext_vector_type(4))) float f32x4;

// split float -> bf16 hi + bf16 residual lo (RNE); hi+lo ~= v to 2^-18 rel
__device__ __forceinline__ void pack_split(float v, unsigned short& h16, unsigned short& l16) {
    unsigned u = __float_as_uint(v);
    unsigned hi = (u + 0x7fffu + ((u >> 16) & 1u)) & 0xffff0000u;
    float lo = v - __uint_as_float(hi);
    unsigned ul = __float_as_uint(lo);
    h16 = (unsigned short)(hi >> 16);
    l16 = (unsigned short)((ul + 0x7fffu + ((ul >> 16) & 1u)) >> 16);
}
__device__ __forceinline__ float bf2f(unsigned short h) {
    return __uint_as_float(((unsigned)h) << 16);
}

// ================= weight conversion: [90][90] f32 -> hi[96][96] + lo[96][96] =================
__global__ __launch_bounds__(256) void convert_w_kernel(const float* __restrict__ w0,
                                                        const float* __restrict__ w1,
                                                        const float* __restrict__ w2,
                                                        const float* __restrict__ w3,
                                                        const float* __restrict__ w4,
                                                        const float* __restrict__ w5,
                                                        unsigned short* __restrict__ wbuf) {
    int m = blockIdx.y;
    const float* src = (m == 0) ? w0 : (m == 1) ? w1 : (m == 2) ? w2
                     : (m == 3) ? w3 : (m == 4) ? w4 : w5;
    unsigned short* dhi = wbuf + (size_t)m * 2 * 96 * 96;
    unsigned short* dlo = dhi + 96 * 96;
    int idx = blockIdx.x * blockDim.x + threadIdx.x;
    if (idx < 96 * 96) {
        int r = idx / 96, c = idx - r * 96;
        float v = (r < H && c < H) ? src[r * H + c] : 0.0f;
        unsigned short h16, l16;
        pack_split(v, h16, l16);
        dhi[idx] = h16;
        dlo[idx] = l16;
    }
}

// ================= CSR build =================
__global__ __launch_bounds__(256) void deg_kernel(const int* __restrict__ dst,
                                                  int* __restrict__ deg) {
    int e = blockIdx.x * blockDim.x + threadIdx.x;
    if (e < N_EDGES) atomicAdd(&deg[dst[e]], 1);
}

#define SCAN_B 512
#define NSB ((N_NODES + SCAN_B - 1) / SCAN_B)   // 98
__global__ __launch_bounds__(SCAN_B) void scan1_kernel(const int* __restrict__ deg,
                                                       int* __restrict__ rowloc,
                                                       int* __restrict__ bsum) {
    __shared__ int s[SCAN_B];
    int t = threadIdx.x;
    int i = blockIdx.x * SCAN_B + t;
    int v = (i < N_NODES) ? deg[i] : 0;
    s[t] = v;
    __syncthreads();
    for (int off = 1; off < SCAN_B; off <<= 1) {
        int u = (t >= off) ? s[t - off] : 0;
        __syncthreads();
        s[t] += u;
        __syncthreads();
    }
    if (i < N_NODES) rowloc[i] = s[t] - v;
    if (t == SCAN_B - 1) bsum[blockIdx.x] = s[t];
}

__global__ __launch_bounds__(128) void scan2_kernel(const int* __restrict__ bsum,
                                                    int* __restrict__ boff) {
    __shared__ int s[128];
    int t = threadIdx.x;
    int v = (t < NSB) ? bsum[t] : 0;
    s[t] = v;
    __syncthreads();
    for (int off = 1; off < 128; off <<= 1) {
        int u = (t >= off) ? s[t - off] : 0;
        __syncthreads();
        s[t] += u;
        __syncthreads();
    }
    boff[t] = s[t] - v;
}

__global__ __launch_bounds__(256) void scan3_kernel(const int* __restrict__ rowloc,
                                                    const int* __restrict__ boff,
                                                    int* __restrict__ rowptr) {
    int i = blockIdx.x * blockDim.x + threadIdx.x;
    if (i < N_NODES) rowptr[i] = rowloc[i] + boff[i / SCAN_B];
    else if (i == N_NODES) rowptr[i] = N_EDGES;
}

// XCD-partitioned fill: block b -> partition p=b&7 (round-robin XCD), chunk b>>3.
// Each partition's csr slice (~0.4 MB) stays in one XCD's L2.
#define FCHUNKS 128
__global__ __launch_bounds__(256) void fill_part_kernel(const int* __restrict__ src,
                                                        const int* __restrict__ dst,
                                                        const int* __restrict__ rowptr,
                                                        int* __restrict__ fill,
                                                        int* __restrict__ csr) {
    const int PART_SZ = N_NODES / 8;                 // 6250
    const int ECH = (N_EDGES + FCHUNKS - 1) / FCHUNKS;
    int p = blockIdx.x & 7;
    int chunk = blockIdx.x >> 3;
    int e0 = chunk * ECH;
    int e1 = min(e0 + ECH, N_EDGES);
    int lo = p * PART_SZ;
    int hi = lo + PART_SZ;
    for (int e = e0 + threadIdx.x; e < e1; e += 256) {
        int d = dst[e];
        if (d >= lo && d < hi) {
            int pos = atomicAdd(&fill[d], 1);
            csr[rowptr[d] + pos] = src[e];
        }
    }
}

// ================= aggregation (wave per node), planes stride PSTRIDE =================
__global__ __launch_bounds__(256) void aggregate_f32_kernel(const float* __restrict__ xin,
                                                            const int* __restrict__ rowptr,
                                                            const int* __restrict__ csr,
                                                            unsigned short* __restrict__ ahi,
                                                            unsigned short* __restrict__ alo) {
    int wv = threadIdx.x >> 6;
    int lane = threadIdx.x & 63;
    int n = blockIdx.x * 4 + wv;           // 12500*4 = 50000 exact
    int r0 = rowptr[n], r1 = rowptr[n + 1];
    float a0 = 0.0f, a1 = 0.0f;
    bool hi = lane < (H - 64);
    int j = r0;
    for (; j + 3 < r1; j += 4) {
        const float* p0 = xin + (size_t)csr[j] * H;
        const float* p1 = xin + (size_t)csr[j + 1] * H;
        const float* p2 = xin + (size_t)csr[j + 2] * H;
        const float* p3 = xin + (size_t)csr[j + 3] * H;
        a0 += p0[lane] + p1[lane] + p2[lane] + p3[lane];
        if (hi) a1 += p0[64 + lane] + p1[64 + lane] + p2[64 + lane] + p3[64 + lane];
    }
    for (; j < r1; ++j) {
        const float* p = xin + (size_t)csr[j] * H;
        a0 += p[lane];
        if (hi) a1 += p[64 + lane];
    }
    float inv = 1.0f / (float)max(r1 - r0, 1);
    unsigned short h16, l16;
    pack_split(a0 * inv, h16, l16);
    ahi[(size_t)n * PSTRIDE + lane] = h16;
    alo[(size_t)n * PSTRIDE + lane] = l16;
    if (hi) {
        pack_split(a1 * inv, h16, l16);
        ahi[(size_t)n * PSTRIDE + 64 + lane] = h16;
        alo[(size_t)n * PSTRIDE + 64 + lane] = l16;
    }
}

__global__ __launch_bounds__(256) void aggregate_hi_kernel(const unsigned short* __restrict__ xhi,
                                                           const int* __restrict__ rowptr,
                                                           const int* __restrict__ csr,
                                                           unsigned short* __restrict__ ahi,
                                                           unsigned short* __restrict__ alo) {
    int wv = threadIdx.x >> 6;
    int lane = threadIdx.x & 63;
    int n = blockIdx.x * 4 + wv;
    int r0 = rowptr[n], r1 = rowptr[n + 1];
    float a0 = 0.0f, a1 = 0.0f;
    bool hi = lane < (H - 64);
    int j = r0;
    for (; j + 3 < r1; j += 4) {
        const unsigned short* p0 = xhi + (size_t)csr[j] * PSTRIDE;
        const unsigned short* p1 = xhi + (size_t)csr[j + 1] * PSTRIDE;
        const unsigned short* p2 = xhi + (size_t)csr[j + 2] * PSTRIDE;
        const unsigned short* p3 = xhi + (size_t)csr[j + 3] * PSTRIDE;
        a0 += bf2f(p0[lane]) + bf2f(p1[lane]) + bf2f(p2[lane]) + bf2f(p3[lane]);
        if (hi) a1 += bf2f(p0[64 + lane]) + bf2f(p1[64 + lane]) +
                      bf2f(p2[64 + lane]) + bf2f(p3[64 + lane]);
    }
    for (; j < r1; ++j) {
        const unsigned short* p = xhi + (size_t)csr[j] * PSTRIDE;
        a0 += bf2f(p[lane]);
        if (hi) a1 += bf2f(p[64 + lane]);
    }
    float inv = 1.0f / (float)max(r1 - r0, 1);
    unsigned short h16, l16;
    pack_split(a0 * inv, h16, l16);
    ahi[(size_t)n * PSTRIDE + lane] = h16;
    alo[(size_t)n * PSTRIDE + lane] = l16;
    if (hi) {
        pack_split(a1 * inv, h16, l16);
        ahi[(size_t)n * PSTRIDE + 64 + lane] = h16;
        alo[(size_t)n * PSTRIDE + 64 + lane] = l16;
    }
}

// ================= combine: LDS-free, fragments direct from global/L2 =================
// Block 256 thr = 4 waves; wave = 16 nodes x 96 h. 108 MFMA + 84 x 16B loads per wave.
// MODE 0: pass1 A packed from raw fp32 x.  MODE 1: planes in/out.  MODE 2: fused pool.
template<int MODE>
__global__ __launch_bounds__(256) void combine_kernel(
        const unsigned short* __restrict__ aghi, const unsigned short* __restrict__ aglo,
        const float* __restrict__ xraw,
        const unsigned short* __restrict__ xhi, const unsigned short* __restrict__ xlo,
        const unsigned short* __restrict__ wl,   // hi plane then lo plane (96*96 each)
        const unsigned short* __restrict__ wr,
        const float* __restrict__ bias,
        unsigned short* __restrict__ ohi, unsigned short* __restrict__ olo,
        const int* __restrict__ batch, float* __restrict__ gs) {
    __shared__ float SG[SGROWS * 96];

    const int tid = threadIdx.x;
    const int lane = tid & 63;
    const int wv = tid >> 6;
    const int node0 = blockIdx.x * 64;
    const int col = lane & 15;
    const int kq = lane >> 4;                       // 0..3
    const int nrow = node0 + wv * 16 + col;         // A-operand node row
    const int nA = min(nrow, N_NODES - 1);

    if (MODE == 2) {
        for (int i = tid; i < SGROWS * 96; i += 256) SG[i] = 0.0f;
        __syncthreads();
    }

    // bias per C-tile column
    float bv[6];
#pragma unroll
    for (int t = 0; t < 6; ++t) {
        int h = t * 16 + col;
        bv[t] = (h < H) ? bias[h] : 0.0f;
    }

    f32x4 acc[6] = {};

#pragma unroll
    for (int pass = 0; pass < 2; ++pass) {
        const unsigned short* wp = pass ? wr : wl;
        bf16x8 Ah[3], Al[3];
        if (pass == 1 && MODE == 0) {
            // pack raw fp32 x fragments in-register
#pragma unroll
            for (int ks = 0; ks < 3; ++ks) {
                int k0 = ks * 32 + kq * 8;
                float f[8];
                if (k0 + 8 <= H) {
#pragma unroll
                    for (int q = 0; q < 4; ++q) {
                        float2 t2 = *reinterpret_cast<const float2*>(
                            xraw + (size_t)nA * H + k0 + q * 2);
                        f[2 * q] = t2.x; f[2 * q + 1] = t2.y;
                    }
                } else {   // k0 == 88: 2 valid, rest 0 (W k-pad is exact zero anyway)
                    float2 t2 = *reinterpret_cast<const float2*>(xraw + (size_t)nA * H + k0);
                    f[0] = t2.x; f[1] = t2.y;
#pragma unroll
                    for (int q = 2; q < 8; ++q) f[q] = 0.0f;
                }
#pragma unroll
                for (int q = 0; q < 8; ++q) {
                    unsigned short hh, ll;
                    pack_split(f[q], hh, ll);
                    Ah[ks][q] = (short)hh;
                    Al[ks][q] = (short)ll;
                }
            }
        } else {
            const unsigned short* ph = pass ? xhi : aghi;
            const unsigned short* pl = pass ? xlo : aglo;
#pragma unroll
            for (int ks = 0; ks < 3; ++ks) {
                size_t off = (size_t)nA * PSTRIDE + ks * 32 + kq * 8;
                Ah[ks] = *reinterpret_cast<const bf16x8*>(ph + off);
                Al[ks] = *reinterpret_cast<const bf16x8*>(pl + off);
            }
        }
#pragma unroll
        for (int ks = 0; ks < 3; ++ks) {
            int kb = ks * 32 + kq * 8;
#pragma unroll
            for (int t = 0; t < 6; ++t) {
                int woff = (t * 16 + col) * 96 + kb;
                bf16x8 Bh = *reinterpret_cast<const bf16x8*>(wp + woff);
                bf16x8 Bl = *reinterpret_cast<const bf16x8*>(wp + 96 * 96 + woff);
                acc[t] = __builtin_amdgcn_mfma_f32_16x16x32_bf16(Ah[ks], Bh, acc[t], 0, 0, 0);
                acc[t] = __builtin_amdgcn_mfma_f32_16x16x32_bf16(Al[ks], Bh, acc[t], 0, 0, 0);
                acc[t] = __builtin_amdgcn_mfma_f32_16x16x32_bf16(Ah[ks], Bl, acc[t], 0, 0, 0);
            }
        }
    }

    // epilogue: C col(h)=lane&15, row(node)=(lane>>4)*4+reg
    int gmin = 0, gnode[4];
    if (MODE == 2) {
        gmin = batch[min(node0, N_NODES - 1)];
#pragma unroll
        for (int r = 0; r < 4; ++r) {
            int node = node0 + wv * 16 + kq * 4 + r;
            gnode[r] = (node < N_NODES) ? batch[node] : -1;
        }
    }
#pragma unroll
    for (int t = 0; t < 6; ++t) {
        int h = t * 16 + col;
        if (h >= H) continue;
#pragma unroll
        for (int r = 0; r < 4; ++r) {
            int node = node0 + wv * 16 + kq * 4 + r;
            if (node >= N_NODES) continue;
            float v = fmaxf(acc[t][r] + bv[t], 0.0f);
            if (MODE == 2) {
                int gl = gnode[r] - gmin;
                if (gl < SGROWS) atomicAdd(&SG[gl * 96 + h], v);
                else atomicAdd(&gs[gnode[r] * H + h], v);
            } else {
                unsigned short h16, l16;
                pack_split(v, h16, l16);
                ohi[(size_t)node * PSTRIDE + h] = h16;
                olo[(size_t)node * PSTRIDE + h] = l16;
            }
        }
    }
    if (MODE == 2) {
        __syncthreads();
        for (int idx = tid; idx < SGROWS * 96; idx += 256) {
            int r = idx / 96, c = idx - r * 96;
            float s = SG[idx];
            if (c < H && s != 0.0f) atomicAdd(&gs[(gmin + r) * H + c], s);
        }
    }
}

// ================= pooling counts =================
__global__ __launch_bounds__(256) void pool_cnt_kernel(const int* __restrict__ batch,
                                                       float* __restrict__ gc) {
    int i = blockIdx.x * blockDim.x + threadIdx.x;
    if (i < N_NODES) atomicAdd(&gc[batch[i]], 1.0f);
}

// ================= MLP head =================
__global__ __launch_bounds__(64) void mlp_kernel(const float* __restrict__ gs,
                                                 const float* __restrict__ gc,
                                                 const float* __restrict__ fc1_w,
                                                 const float* __restrict__ fc1_b,
                                                 const float* __restrict__ fc2_w,
                                                 const float* __restrict__ fc2_b,
                                                 float* __restrict__ out) {
    int g = blockIdx.x;
    int t = threadIdx.x;
    __shared__ float h4[H];
    float inv = 1.0f / fmaxf(gc[g], 1.0f);
    for (int k = t; k < H; k += 64) h4[k] = gs[g * H + k] * inv;
    __syncthreads();
    float v = 0.0f;
    if (t < 32) {
        float acc = fc1_b[t];
#pragma unroll 6
        for (int k = 0; k < H; ++k) acc += h4[k] * fc1_w[t * H + k];
        v = fmaxf(acc, 0.0f) * fc2_w[t];
    }
    for (int off = 16; off; off >>= 1) v += __shfl_down(v, off, 32);
    if (t == 0) out[g] = v + fc2_b[0];
}

extern "C" void kernel_launch(void* const* d_in, const int* in_sizes, int n_in,
                              void* d_out, int out_size, void* d_ws, size_t ws_size,
                              hipStream_t stream) {
    const float* x     = (const float*)d_in[0];
    const int*   ei    = (const int*)d_in[1];
    const int*   batch = (const int*)d_in[2];
    const float* W1l = (const float*)d_in[3];
    const float* b1l = (const float*)d_in[4];
    const float* W1r = (const float*)d_in[5];
    const float* W2l = (const float*)d_in[6];
    const float* b2l = (const float*)d_in[7];
    const float* W2r = (const float*)d_in[8];
    const float* W3l = (const float*)d_in[9];
    const float* b3l = (const float*)d_in[10];
    const float* W3r = (const float*)d_in[11];
    const float* fc1_w = (const float*)d_in[12];
    const float* fc1_b = (const float*)d_in[13];
    const float* fc2_w = (const float*)d_in[14];
    const float* fc2_b = (const float*)d_in[15];

    const int* src = ei;
    const int* dst = ei + N_EDGES;

    // ---- workspace layout (~59 MB) ----
    const size_t NP = (size_t)N_NODES * PSTRIDE;     // 4.8M elems, 9.216 MB/plane
    unsigned short* P0h = (unsigned short*)d_ws;
    unsigned short* P0l = P0h + NP;
    unsigned short* P1h = P0l + NP;
    unsigned short* P1l = P1h + NP;
    unsigned short* AGh = P1l + NP;
    unsigned short* AGl = AGh + NP;
    int* csr    = (int*)(AGl + NP);                  // 3.2 MB
    int* rowptr = csr + N_EDGES;                     // 200 KB
    unsigned short* wbuf = (unsigned short*)(rowptr + N_NODES + 1);  // 6*2*9216 u16
    float* gs = (float*)(wbuf + 6 * 2 * 96 * 96);
    float* gc = gs + N_GRAPHS * H;

    // CSR-build temporaries aliased into AG planes (dead before first aggregate)
    int* deg    = (int*)AGh;
    int* fil    = deg + N_NODES;
    int* rowloc = fil + N_NODES;
    int* bsum   = rowloc + N_NODES;
    int* boff   = bsum + 128;

    const unsigned short* wb1l = wbuf + 0 * 2 * 96 * 96;
    const unsigned short* wb1r = wbuf + 1 * 2 * 96 * 96;
    const unsigned short* wb2l = wbuf + 2 * 2 * 96 * 96;
    const unsigned short* wb2r = wbuf + 3 * 2 * 96 * 96;
    const unsigned short* wb3l = wbuf + 4 * 2 * 96 * 96;
    const unsigned short* wb3r = wbuf + 5 * 2 * 96 * 96;

    float* out = (float*)d_out;

    const int edgeBlocks = (N_EDGES + 255) / 256;
    const int combBlocks = (N_NODES + 63) / 64;      // 782
    const int aggBlocks  = N_NODES / 4;              // 12500

    convert_w_kernel<<<dim3(36, 6), 256, 0, stream>>>(W1l, W1r, W2l, W2r, W3l, W3r, wbuf);

    // ---- CSR build ----
    hipMemsetAsync(deg, 0, 2 * N_NODES * sizeof(int), stream);  // deg + fil
    deg_kernel<<<edgeBlocks, 256, 0, stream>>>(dst, deg);
    scan1_kernel<<<NSB, SCAN_B, 0, stream>>>(deg, rowloc, bsum);
    scan2_kernel<<<1, 128, 0, stream>>>(bsum, boff);
    scan3_kernel<<<(N_NODES + 256) / 256, 256, 0, stream>>>(rowloc, boff, rowptr);
    fill_part_kernel<<<FCHUNKS * 8, 256, 0, stream>>>(src, dst, rowptr, fil, csr);

    // pool setup
    hipMemsetAsync(gs, 0, (N_GRAPHS * H + N_GRAPHS) * sizeof(float), stream);
    pool_cnt_kernel<<<(N_NODES + 255) / 256, 256, 0, stream>>>(batch, gc);

    // ---- layer 1: x (fp32) -> P0 planes ----
    aggregate_f32_kernel<<<aggBlocks, 256, 0, stream>>>(x, rowptr, csr, AGh, AGl);
    combine_kernel<0><<<combBlocks, 256, 0, stream>>>(AGh, AGl, x, nullptr, nullptr,
                                                      wb1l, wb1r, b1l, P0h, P0l,
                                                      nullptr, nullptr);
    // ---- layer 2: P0 -> P1 ----
    aggregate_hi_kernel<<<aggBlocks, 256, 0, stream>>>(P0h, rowptr, csr, AGh, AGl);
    combine_kernel<1><<<combBlocks, 256, 0, stream>>>(AGh, AGl, nullptr, P0h, P0l,
                                                      wb2l, wb2r, b2l, P1h, P1l,
                                                      nullptr, nullptr);
    // ---- layer 3: P1 -> fused pool into gs ----
    aggregate_hi_kernel<<<aggBlocks, 256, 0, stream>>>(P1h, rowptr, csr, AGh, AGl);
    combine_kernel<2><<<combBlocks, 256, 0, stream>>>(AGh, AGl, nullptr, P1h, P1l,
                                                      wb3l, wb3r, b3l, nullptr, nullptr,
                                                      batch, gs);

    // ---- MLP head ----
    mlp_kernel<<<N_GRAPHS, 64, 0, stream>>>(gs, gc, fc1_w, fc1_b, fc2_w, fc2_b, out);
}

// Round 6
// 368.590 us; speedup vs baseline: 3.9919x; 1.0142x over previous
//
#include <hip/hip_runtime.h>
#include <hip/hip_bf16.h>

#define N_NODES 50000
#define N_EDGES 800000
#define N_GRAPHS 500
#define H 90
#define PSTRIDE 96     // padded plane row stride (u16 elems) -> 192 B, 16B-aligned rows
#define SGROWS 8

typedef __attribute__((ext_vector_type(8))) short bf16x8;
typedef __attribute__((ext_vector_type(4))) float f32x4;

// split float -> bf16 hi + bf16 residual lo (RNE); hi+lo ~= v to 2^-18 rel
__device__ __forceinline__ void pack_split(float v, unsigned short& h16, unsigned short& l16) {
    unsigned u = __float_as_uint(v);
    unsigned hi = (u + 0x7fffu + ((u >> 16) & 1u)) & 0xffff0000u;
    float lo = v - __uint_as_float(hi);
    unsigned ul = __float_as_uint(lo);
    h16 = (unsigned short)(hi >> 16);
    l16 = (unsigned short)((ul + 0x7fffu + ((ul >> 16) & 1u)) >> 16);
}
__device__ __forceinline__ float bf2f(unsigned short h) {
    return __uint_as_float(((unsigned)h) << 16);
}

// ================= weight conversion: [90][90] f32 -> hi[96][96] + lo[96][96] =================
__global__ __launch_bounds__(256) void convert_w_kernel(const float* __restrict__ w0,
                                                        const float* __restrict__ w1,
                                                        const float* __restrict__ w2,
                                                        const float* __restrict__ w3,
                                                        const float* __restrict__ w4,
                                                        const float* __restrict__ w5,
                                                        unsigned short* __restrict__ wbuf) {
    int m = blockIdx.y;
    const float* src = (m == 0) ? w0 : (m == 1) ? w1 : (m == 2) ? w2
                     : (m == 3) ? w3 : (m == 4) ? w4 : w5;
    unsigned short* dhi = wbuf + (size_t)m * 2 * 96 * 96;
    unsigned short* dlo = dhi + 96 * 96;
    int idx = blockIdx.x * blockDim.x + threadIdx.x;
    if (idx < 96 * 96) {
        int r = idx / 96, c = idx - r * 96;
        float v = (r < H && c < H) ? src[r * H + c] : 0.0f;
        unsigned short h16, l16;
        pack_split(v, h16, l16);
        dhi[idx] = h16;
        dlo[idx] = l16;
    }
}

// ================= CSR build =================
__global__ __launch_bounds__(256) void deg_kernel(const int* __restrict__ dst,
                                                  int* __restrict__ deg) {
    int e = blockIdx.x * blockDim.x + threadIdx.x;
    if (e < N_EDGES) atomicAdd(&deg[dst[e]], 1);
}

#define SCAN_B 512
#define NSB ((N_NODES + SCAN_B - 1) / SCAN_B)   // 98
__global__ __launch_bounds__(SCAN_B) void scan1_kernel(const int* __restrict__ deg,
                                                       int* __restrict__ rowloc,
                                                       int* __restrict__ bsum) {
    __shared__ int s[SCAN_B];
    int t = threadIdx.x;
    int i = blockIdx.x * SCAN_B + t;
    int v = (i < N_NODES) ? deg[i] : 0;
    s[t] = v;
    __syncthreads();
    for (int off = 1; off < SCAN_B; off <<= 1) {
        int u = (t >= off) ? s[t - off] : 0;
        __syncthreads();
        s[t] += u;
        __syncthreads();
    }
    if (i < N_NODES) rowloc[i] = s[t] - v;
    if (t == SCAN_B - 1) bsum[blockIdx.x] = s[t];
}

__global__ __launch_bounds__(128) void scan2_kernel(const int* __restrict__ bsum,
                                                    int* __restrict__ boff) {
    __shared__ int s[128];
    int t = threadIdx.x;
    int v = (t < NSB) ? bsum[t] : 0;
    s[t] = v;
    __syncthreads();
    for (int off = 1; off < 128; off <<= 1) {
        int u = (t >= off) ? s[t - off] : 0;
        __syncthreads();
        s[t] += u;
        __syncthreads();
    }
    boff[t] = s[t] - v;
}

__global__ __launch_bounds__(256) void scan3_kernel(const int* __restrict__ rowloc,
                                                    const int* __restrict__ boff,
                                                    int* __restrict__ rowptr) {
    int i = blockIdx.x * blockDim.x + threadIdx.x;
    if (i < N_NODES) rowptr[i] = rowloc[i] + boff[i / SCAN_B];
    else if (i == N_NODES) rowptr[i] = N_EDGES;
}

// XCD-partitioned fill
#define FCHUNKS 128
__global__ __launch_bounds__(256) void fill_part_kernel(const int* __restrict__ src,
                                                        const int* __restrict__ dst,
                                                        const int* __restrict__ rowptr,
                                                        int* __restrict__ fill,
                                                        int* __restrict__ csr) {
    const int PART_SZ = N_NODES / 8;                 // 6250
    const int ECH = (N_EDGES + FCHUNKS - 1) / FCHUNKS;
    int p = blockIdx.x & 7;
    int chunk = blockIdx.x >> 3;
    int e0 = chunk * ECH;
    int e1 = min(e0 + ECH, N_EDGES);
    int lo = p * PART_SZ;
    int hi = lo + PART_SZ;
    for (int e = e0 + threadIdx.x; e < e1; e += 256) {
        int d = dst[e];
        if (d >= lo && d < hi) {
            int pos = atomicAdd(&fill[d], 1);
            csr[rowptr[d] + pos] = src[e];
        }
    }
}

// ================= aggregation (wave per node), planes stride PSTRIDE =================
__global__ __launch_bounds__(256) void aggregate_f32_kernel(const float* __restrict__ xin,
                                                            const int* __restrict__ rowptr,
                                                            const int* __restrict__ csr,
                                                            unsigned short* __restrict__ ahi,
                                                            unsigned short* __restrict__ alo) {
    int wv = threadIdx.x >> 6;
    int lane = threadIdx.x & 63;
    int n = blockIdx.x * 4 + wv;           // 12500*4 = 50000 exact
    int r0 = rowptr[n], r1 = rowptr[n + 1];
    float a0 = 0.0f, a1 = 0.0f;
    bool hi = lane < (H - 64);
    int j = r0;
    for (; j + 3 < r1; j += 4) {
        const float* p0 = xin + (size_t)csr[j] * H;
        const float* p1 = xin + (size_t)csr[j + 1] * H;
        const float* p2 = xin + (size_t)csr[j + 2] * H;
        const float* p3 = xin + (size_t)csr[j + 3] * H;
        a0 += p0[lane] + p1[lane] + p2[lane] + p3[lane];
        if (hi) a1 += p0[64 + lane] + p1[64 + lane] + p2[64 + lane] + p3[64 + lane];
    }
    for (; j < r1; ++j) {
        const float* p = xin + (size_t)csr[j] * H;
        a0 += p[lane];
        if (hi) a1 += p[64 + lane];
    }
    float inv = 1.0f / (float)max(r1 - r0, 1);
    unsigned short h16, l16;
    pack_split(a0 * inv, h16, l16);
    ahi[(size_t)n * PSTRIDE + lane] = h16;
    alo[(size_t)n * PSTRIDE + lane] = l16;
    if (hi) {
        pack_split(a1 * inv, h16, l16);
        ahi[(size_t)n * PSTRIDE + 64 + lane] = h16;
        alo[(size_t)n * PSTRIDE + 64 + lane] = l16;
    }
}

__global__ __launch_bounds__(256) void aggregate_hi_kernel(const unsigned short* __restrict__ xhi,
                                                           const int* __restrict__ rowptr,
                                                           const int* __restrict__ csr,
                                                           unsigned short* __restrict__ ahi,
                                                           unsigned short* __restrict__ alo) {
    int wv = threadIdx.x >> 6;
    int lane = threadIdx.x & 63;
    int n = blockIdx.x * 4 + wv;
    int r0 = rowptr[n], r1 = rowptr[n + 1];
    float a0 = 0.0f, a1 = 0.0f;
    bool hi = lane < (H - 64);
    int j = r0;
    for (; j + 3 < r1; j += 4) {
        const unsigned short* p0 = xhi + (size_t)csr[j] * PSTRIDE;
        const unsigned short* p1 = xhi + (size_t)csr[j + 1] * PSTRIDE;
        const unsigned short* p2 = xhi + (size_t)csr[j + 2] * PSTRIDE;
        const unsigned short* p3 = xhi + (size_t)csr[j + 3] * PSTRIDE;
        a0 += bf2f(p0[lane]) + bf2f(p1[lane]) + bf2f(p2[lane]) + bf2f(p3[lane]);
        if (hi) a1 += bf2f(p0[64 + lane]) + bf2f(p1[64 + lane]) +
                      bf2f(p2[64 + lane]) + bf2f(p3[64 + lane]);
    }
    for (; j < r1; ++j) {
        const unsigned short* p = xhi + (size_t)csr[j] * PSTRIDE;
        a0 += bf2f(p[lane]);
        if (hi) a1 += bf2f(p[64 + lane]);
    }
    float inv = 1.0f / (float)max(r1 - r0, 1);
    unsigned short h16, l16;
    pack_split(a0 * inv, h16, l16);
    ahi[(size_t)n * PSTRIDE + lane] = h16;
    alo[(size_t)n * PSTRIDE + lane] = l16;
    if (hi) {
        pack_split(a1 * inv, h16, l16);
        ahi[(size_t)n * PSTRIDE + 64 + lane] = h16;
        alo[(size_t)n * PSTRIDE + 64 + lane] = l16;
    }
}

// ================= combine: LDS-free, k-slice-batched loads =================
// Block 256 thr = 4 waves; wave = 16 nodes x 48 h (3 C-tiles).
// Per k-slice: 8 loads issued together -> ONE vmcnt wait -> 9 MFMAs.
// MODE 0: pass1 A packed from raw fp32 x.  MODE 1: planes in/out.  MODE 2: fused pool.
template<int MODE>
__global__ __launch_bounds__(256) void combine_kernel(
        const unsigned short* __restrict__ aghi, const unsigned short* __restrict__ aglo,
        const float* __restrict__ xraw,
        const unsigned short* __restrict__ xhi, const unsigned short* __restrict__ xlo,
        const unsigned short* __restrict__ wl,   // hi plane then lo plane (96*96 each)
        const unsigned short* __restrict__ wr,
        const float* __restrict__ bias,
        unsigned short* __restrict__ ohi, unsigned short* __restrict__ olo,
        const int* __restrict__ batch, float* __restrict__ gs) {
    __shared__ float SG[SGROWS * 96];

    const int tid = threadIdx.x;
    const int lane = tid & 63;
    const int wv = tid >> 6;
    const int nhalf = wv >> 1;                      // node stripe 0..1
    const int hhalf = wv & 1;                       // h stripe 0..1
    const int blk0 = blockIdx.x * 32;
    const int node0 = blk0 + nhalf * 16;            // wave's 16-node stripe
    const int col = lane & 15;
    const int kq = lane >> 4;                       // 0..3
    const int tbase = hhalf * 3;
    const int nrow = node0 + col;                   // A-operand node row
    const int nA = min(nrow, N_NODES - 1);

    if (MODE == 2) {
        for (int i = tid; i < SGROWS * 96; i += 256) SG[i] = 0.0f;
        __syncthreads();
    }

    float bv[3];
#pragma unroll
    for (int t = 0; t < 3; ++t) {
        int h = (tbase + t) * 16 + col;
        bv[t] = (h < H) ? bias[h] : 0.0f;
    }

    f32x4 acc[3] = {};

#pragma unroll
    for (int pass = 0; pass < 2; ++pass) {
        const unsigned short* wp = pass ? wr : wl;
#pragma unroll
        for (int ks = 0; ks < 3; ++ks) {
            // ---- issue ALL loads for this k-slice together ----
            bf16x8 Bh[3], Bl[3];
            const int kb = ks * 32 + kq * 8;
#pragma unroll
            for (int t = 0; t < 3; ++t) {
                int woff = ((tbase + t) * 16 + col) * 96 + kb;
                Bh[t] = *reinterpret_cast<const bf16x8*>(wp + woff);
                Bl[t] = *reinterpret_cast<const bf16x8*>(wp + 96 * 96 + woff);
            }
            bf16x8 Ah, Al;
            if (pass == 1 && MODE == 0) {
                int k0 = ks * 32 + kq * 8;
                float f[8];
                if (k0 + 8 <= H) {
#pragma unroll
                    for (int q = 0; q < 4; ++q) {
                        float2 t2 = *reinterpret_cast<const float2*>(
                            xraw + (size_t)nA * H + k0 + q * 2);
                        f[2 * q] = t2.x; f[2 * q + 1] = t2.y;
                    }
                } else {   // k0 == 88
                    float2 t2 = *reinterpret_cast<const float2*>(xraw + (size_t)nA * H + k0);
                    f[0] = t2.x; f[1] = t2.y;
#pragma unroll
                    for (int q = 2; q < 8; ++q) f[q] = 0.0f;
                }
#pragma unroll
                for (int q = 0; q < 8; ++q) {
                    unsigned short hh, ll;
                    pack_split(f[q], hh, ll);
                    Ah[q] = (short)hh;
                    Al[q] = (short)ll;
                }
            } else {
                const unsigned short* ph = pass ? xhi : aghi;
                const unsigned short* pl = pass ? xlo : aglo;
                size_t off = (size_t)nA * PSTRIDE + kb;
                Ah = *reinterpret_cast<const bf16x8*>(ph + off);
                Al = *reinterpret_cast<const bf16x8*>(pl + off);
            }
            // ---- 9 MFMAs on the batch ----
#pragma unroll
            for (int t = 0; t < 3; ++t) {
                acc[t] = __builtin_amdgcn_mfma_f32_16x16x32_bf16(Ah, Bh[t], acc[t], 0, 0, 0);
                acc[t] = __builtin_amdgcn_mfma_f32_16x16x32_bf16(Al, Bh[t], acc[t], 0, 0, 0);
                acc[t] = __builtin_amdgcn_mfma_f32_16x16x32_bf16(Ah, Bl[t], acc[t], 0, 0, 0);
            }
        }
    }

    // ---- epilogue: C col(h)=lane&15, row(node)=kq*4+reg within stripe ----
    int gmin = 0, gnode[4];
    if (MODE == 2) {
        gmin = batch[blk0];
#pragma unroll
        for (int r = 0; r < 4; ++r) {
            int node = node0 + kq * 4 + r;
            gnode[r] = (node < N_NODES) ? batch[node] : -1;
        }
    }
#pragma unroll
    for (int t = 0; t < 3; ++t) {
        int h = (tbase + t) * 16 + col;
        if (h >= H) continue;
#pragma unroll
        for (int r = 0; r < 4; ++r) {
            int node = node0 + kq * 4 + r;
            if (node >= N_NODES) continue;
            float v = fmaxf(acc[t][r] + bv[t], 0.0f);
            if (MODE == 2) {
                int gl = gnode[r] - gmin;
                if (gl < SGROWS) atomicAdd(&SG[gl * 96 + h], v);
                else atomicAdd(&gs[gnode[r] * H + h], v);
            } else {
                unsigned short h16, l16;
                pack_split(v, h16, l16);
                ohi[(size_t)node * PSTRIDE + h] = h16;
                olo[(size_t)node * PSTRIDE + h] = l16;
            }
        }
    }
    if (MODE == 2) {
        __syncthreads();
        for (int idx = tid; idx < SGROWS * 96; idx += 256) {
            int r = idx / 96, c = idx - r * 96;
            float s = SG[idx];
            if (c < H && s != 0.0f) atomicAdd(&gs[(gmin + r) * H + c], s);
        }
    }
}

// ================= pooling counts =================
__global__ __launch_bounds__(256) void pool_cnt_kernel(const int* __restrict__ batch,
                                                       float* __restrict__ gc) {
    int i = blockIdx.x * blockDim.x + threadIdx.x;
    if (i < N_NODES) atomicAdd(&gc[batch[i]], 1.0f);
}

// ================= MLP head =================
__global__ __launch_bounds__(64) void mlp_kernel(const float* __restrict__ gs,
                                                 const float* __restrict__ gc,
                                                 const float* __restrict__ fc1_w,
                                                 const float* __restrict__ fc1_b,
                                                 const float* __restrict__ fc2_w,
                                                 const float* __restrict__ fc2_b,
                                                 float* __restrict__ out) {
    int g = blockIdx.x;
    int t = threadIdx.x;
    __shared__ float h4[H];
    float inv = 1.0f / fmaxf(gc[g], 1.0f);
    for (int k = t; k < H; k += 64) h4[k] = gs[g * H + k] * inv;
    __syncthreads();
    float v = 0.0f;
    if (t < 32) {
        float acc = fc1_b[t];
#pragma unroll 6
        for (int k = 0; k < H; ++k) acc += h4[k] * fc1_w[t * H + k];
        v = fmaxf(acc, 0.0f) * fc2_w[t];
    }
    for (int off = 16; off; off >>= 1) v += __shfl_down(v, off, 32);
    if (t == 0) out[g] = v + fc2_b[0];
}

extern "C" void kernel_launch(void* const* d_in, const int* in_sizes, int n_in,
                              void* d_out, int out_size, void* d_ws, size_t ws_size,
                              hipStream_t stream) {
    const float* x     = (const float*)d_in[0];
    const int*   ei    = (const int*)d_in[1];
    const int*   batch = (const int*)d_in[2];
    const float* W1l = (const float*)d_in[3];
    const float* b1l = (const float*)d_in[4];
    const float* W1r = (const float*)d_in[5];
    const float* W2l = (const float*)d_in[6];
    const float* b2l = (const float*)d_in[7];
    const float* W2r = (const float*)d_in[8];
    const float* W3l = (const float*)d_in[9];
    const float* b3l = (const float*)d_in[10];
    const float* W3r = (const float*)d_in[11];
    const float* fc1_w = (const float*)d_in[12];
    const float* fc1_b = (const float*)d_in[13];
    const float* fc2_w = (const float*)d_in[14];
    const float* fc2_b = (const float*)d_in[15];

    const int* src = ei;
    const int* dst = ei + N_EDGES;

    // ---- workspace layout (~59 MB) ----
    const size_t NP = (size_t)N_NODES * PSTRIDE;     // 4.8M elems, 9.216 MB/plane
    unsigned short* P0h = (unsigned short*)d_ws;
    unsigned short* P0l = P0h + NP;
    unsigned short* P1h = P0l + NP;
    unsigned short* P1l = P1h + NP;
    unsigned short* AGh = P1l + NP;
    unsigned short* AGl = AGh + NP;
    int* csr    = (int*)(AGl + NP);                  // 3.2 MB
    int* rowptr = csr + N_EDGES;                     // 200 KB
    unsigned short* wbuf = (unsigned short*)(rowptr + N_NODES + 1);  // 6*2*9216 u16
    float* gs = (float*)(wbuf + 6 * 2 * 96 * 96);
    float* gc = gs + N_GRAPHS * H;

    // CSR-build temporaries aliased into AG planes (dead before first aggregate)
    int* deg    = (int*)AGh;
    int* fil    = deg + N_NODES;
    int* rowloc = fil + N_NODES;
    int* bsum   = rowloc + N_NODES;
    int* boff   = bsum + 128;

    const unsigned short* wb1l = wbuf + 0 * 2 * 96 * 96;
    const unsigned short* wb1r = wbuf + 1 * 2 * 96 * 96;
    const unsigned short* wb2l = wbuf + 2 * 2 * 96 * 96;
    const unsigned short* wb2r = wbuf + 3 * 2 * 96 * 96;
    const unsigned short* wb3l = wbuf + 4 * 2 * 96 * 96;
    const unsigned short* wb3r = wbuf + 5 * 2 * 96 * 96;

    float* out = (float*)d_out;

    const int edgeBlocks = (N_EDGES + 255) / 256;
    const int combBlocks = (N_NODES + 31) / 32;      // 1563
    const int aggBlocks  = N_NODES / 4;              // 12500

    convert_w_kernel<<<dim3(36, 6), 256, 0, stream>>>(W1l, W1r, W2l, W2r, W3l, W3r, wbuf);

    // ---- CSR build ----
    hipMemsetAsync(deg, 0, 2 * N_NODES * sizeof(int), stream);  // deg + fil
    deg_kernel<<<edgeBlocks, 256, 0, stream>>>(dst, deg);
    scan1_kernel<<<NSB, SCAN_B, 0, stream>>>(deg, rowloc, bsum);
    scan2_kernel<<<1, 128, 0, stream>>>(bsum, boff);
    scan3_kernel<<<(N_NODES + 256) / 256, 256, 0, stream>>>(rowloc, boff, rowptr);
    fill_part_kernel<<<FCHUNKS * 8, 256, 0, stream>>>(src, dst, rowptr, fil, csr);

    // pool setup
    hipMemsetAsync(gs, 0, (N_GRAPHS * H + N_GRAPHS) * sizeof(float), stream);
    pool_cnt_kernel<<<(N_NODES + 255) / 256, 256, 0, stream>>>(batch, gc);

    // ---- layer 1: x (fp32) -> P0 planes ----
    aggregate_f32_kernel<<<aggBlocks, 256, 0, stream>>>(x, rowptr, csr, AGh, AGl);
    combine_kernel<0><<<combBlocks, 256, 0, stream>>>(AGh, AGl, x, nullptr, nullptr,
                                                      wb1l, wb1r, b1l, P0h, P0l,
                                                      nullptr, nullptr);
    // ---- layer 2: P0 -> P1 ----
    aggregate_hi_kernel<<<aggBlocks, 256, 0, stream>>>(P0h, rowptr, csr, AGh, AGl);
    combine_kernel<1><<<combBlocks, 256, 0, stream>>>(AGh, AGl, nullptr, P0h, P0l,
                                                      wb2l, wb2r, b2l, P1h, P1l,
                                                      nullptr, nullptr);
    // ---- layer 3: P1 -> fused pool into gs ----
    aggregate_hi_kernel<<<aggBlocks, 256, 0, stream>>>(P1h, rowptr, csr, AGh, AGl);
    combine_kernel<2><<<combBlocks, 256, 0, stream>>>(AGh, AGl, nullptr, P1h, P1l,
                                                      wb3l, wb3r, b3l, nullptr, nullptr,
                                                      batch, gs);

    // ---- MLP head ----
    mlp_kernel<<<N_GRAPHS, 64, 0, stream>>>(gs, gc, fc1_w, fc1_b, fc2_w, fc2_b, out);
}